// Round 13
// baseline (425.559 us; speedup 1.0000x reference)
//
#include <hip/hip_runtime.h>

#define DD 64
#define SCAN_T 1024
#define DTILE 128

// ---------- CSR build ----------

// histogram + per-edge rank within its dst (rank = atomic return value)
__global__ __launch_bounds__(256)
void hist_kernel(const int* __restrict__ dst, int* __restrict__ degi,
                 int* __restrict__ rank, int nE)
{
    for (int e = blockIdx.x * blockDim.x + threadIdx.x; e < nE;
         e += gridDim.x * blockDim.x) {
        int r = atomicAdd(&degi[dst[e]], 1);
        rank[e] = r;
    }
}

__global__ __launch_bounds__(SCAN_T)
void scan1_kernel(const int* __restrict__ degi, int* __restrict__ rs,
                  int* __restrict__ partials, int nN)
{
    __shared__ int s[SCAN_T];
    int tid = threadIdx.x;
    int gid = blockIdx.x * SCAN_T + tid;
    int v = (gid < nN) ? degi[gid] : 0;
    s[tid] = v;
    __syncthreads();
    for (int off = 1; off < SCAN_T; off <<= 1) {
        int t = (tid >= off) ? s[tid - off] : 0;
        __syncthreads();
        s[tid] += t;
        __syncthreads();
    }
    if (gid < nN) rs[gid] = s[tid] - v;   // exclusive
    if (tid == SCAN_T - 1) partials[blockIdx.x] = s[SCAN_T - 1];
}

// wave-parallel exclusive scan over <=128 block partials
__global__ void scan2_kernel(int* __restrict__ partials, int* __restrict__ rs,
                             int nblk, int nN)
{
    int lane = threadIdx.x;   // 64 threads
    int p0 = (lane < nblk) ? partials[lane] : 0;
    int p1 = (64 + lane < nblk) ? partials[64 + lane] : 0;
    int v0 = p0;
    for (int off = 1; off < 64; off <<= 1) {
        int t = __shfl_up(v0, off);
        if (lane >= off) v0 += t;
    }
    int total0 = __shfl(v0, 63);
    int v1 = p1;
    for (int off = 1; off < 64; off <<= 1) {
        int t = __shfl_up(v1, off);
        if (lane >= off) v1 += t;
    }
    int grand = total0 + __shfl(v1, 63);
    if (lane < nblk) partials[lane] = v0 - p0;
    if (64 + lane < nblk) partials[64 + lane] = total0 + v1 - p1;
    if (lane == 0) rs[nN] = grand;   // == nE
}

__global__ __launch_bounds__(SCAN_T)
void scan3_kernel(int* __restrict__ rs, const int* __restrict__ partials, int nN)
{
    int gid = blockIdx.x * SCAN_T + threadIdx.x;
    if (gid < nN) rs[gid] += partials[blockIdx.x];
}

// scatter src into CSR slot rs[d]+rank[e] — NO atomics
__global__ __launch_bounds__(256)
void fill_kernel(const int* __restrict__ src, const int* __restrict__ dst,
                 const int* __restrict__ rs, const int* __restrict__ rank,
                 int* __restrict__ csr, int nE)
{
    for (int e = blockIdx.x * blockDim.x + threadIdx.x; e < nE;
         e += gridDim.x * blockDim.x) {
        csr[rs[dst[e]] + rank[e]] = src[e];
    }
}

// ---------- weight precompute: collapse the two layers ----------
// MT1 = (W2l*W1l)^T ; MT2 = (W2l*W1r + W2r*W1l)^T ; MT3 = (W2r*W1r)^T
// stored TRANSPOSED: MT[k*DD+f] so the dense kernel's per-k scalar row
// loads are contiguous. c1 = b1 @ W2l.T ; c0 = b1 @ W2r.T + b2
// out = agg2@M1.T + agg1@M2.T + x@M3.T + ind*c1 + c0
__global__ void prep_kernel(const float* __restrict__ W1l,
                            const float* __restrict__ W1r,
                            const float* __restrict__ W2l,
                            const float* __restrict__ W2r,
                            const float* __restrict__ b1,
                            const float* __restrict__ b2,
                            float* __restrict__ MT1, float* __restrict__ MT2,
                            float* __restrict__ MT3, float* __restrict__ c0,
                            float* __restrict__ c1)
{
    int f = blockIdx.x;      // 64 blocks
    int k = threadIdx.x;     // 64 threads
    float m1 = 0.f, m2 = 0.f, m3 = 0.f;
    for (int j = 0; j < DD; ++j) {
        float a2l = W2l[f * DD + j];
        float a2r = W2r[f * DD + j];
        float w1l = W1l[j * DD + k];
        float w1r = W1r[j * DD + k];
        m1 = fmaf(a2l, w1l, m1);
        m2 = fmaf(a2l, w1r, m2);
        m2 = fmaf(a2r, w1l, m2);
        m3 = fmaf(a2r, w1r, m3);
    }
    MT1[k * DD + f] = m1;
    MT2[k * DD + f] = m2;
    MT3[k * DD + f] = m3;
    float t1 = W2l[f * DD + k] * b1[k];
    float t0 = W2r[f * DD + k] * b1[k];
    for (int off = 1; off < 64; off <<= 1) {
        t1 += __shfl_xor(t1, off);
        t0 += __shfl_xor(t0, off);
    }
    if (k == 0) {
        c1[f] = t1;
        c0[f] = t0 + b2[f];
    }
}

// ---------- aggregation: mean over neighbors ----------
// Wave per node; 16-lane group g takes rows {j+g, j+4+g, ..., j+28+g}:
// EIGHT independent float4 gathers in flight per step. Branch-free.
__global__ __launch_bounds__(256, 4)
void aggregate_kernel(const float* __restrict__ xin,
                      const int* __restrict__ csr,
                      const int* __restrict__ rs,
                      float* __restrict__ aggr, int nN)
{
    int lane = threadIdx.x & 63;
    int w = threadIdx.x >> 6;
    int g  = lane >> 4;        // group 0..3
    int gl = lane & 15;        // lane within group
    int totWaves = gridDim.x * 4;
    for (int node = blockIdx.x * 4 + w; node < nN; node += totWaves) {
        int beg = rs[node], end = rs[node + 1];
        int deg = end - beg;
        float4 a0 = {0,0,0,0}, a1 = {0,0,0,0}, a2 = {0,0,0,0}, a3 = {0,0,0,0};
        float4 a4 = {0,0,0,0}, a5 = {0,0,0,0}, a6 = {0,0,0,0}, a7 = {0,0,0,0};
        for (int base = beg; base < end; base += 64) {
            int n = end - base;
            if (n > 64) n = 64;
            // lanes >= n read csr[base] (valid, hot) so shfl'd idx are safe
            int myIdx = csr[(lane < n) ? (base + lane) : base];
            for (int j = 0; j < n; j += 32) {
#define GSLOT(ACC, OFS)                                                       \
                {                                                             \
                    int ii = j + (OFS) + g;                                   \
                    int si = __shfl(myIdx, ii & 63);                          \
                    float mm = (ii < n) ? 1.f : 0.f;                          \
                    float4 v = *(const float4*)(xin + (size_t)si * DD + gl * 4);\
                    ACC.x = fmaf(mm, v.x, ACC.x);                             \
                    ACC.y = fmaf(mm, v.y, ACC.y);                             \
                    ACC.z = fmaf(mm, v.z, ACC.z);                             \
                    ACC.w = fmaf(mm, v.w, ACC.w);                             \
                }
                GSLOT(a0, 0)  GSLOT(a1, 4)  GSLOT(a2, 8)  GSLOT(a3, 12)
                GSLOT(a4, 16) GSLOT(a5, 20) GSLOT(a6, 24) GSLOT(a7, 28)
#undef GSLOT
            }
        }
        float sx = ((a0.x + a1.x) + (a2.x + a3.x)) + ((a4.x + a5.x) + (a6.x + a7.x));
        float sy = ((a0.y + a1.y) + (a2.y + a3.y)) + ((a4.y + a5.y) + (a6.y + a7.y));
        float sz = ((a0.z + a1.z) + (a2.z + a3.z)) + ((a4.z + a5.z) + (a6.z + a7.z));
        float sw = ((a0.w + a1.w) + (a2.w + a3.w)) + ((a4.w + a5.w) + (a6.w + a7.w));
        sx += __shfl_xor(sx, 16); sy += __shfl_xor(sy, 16);
        sz += __shfl_xor(sz, 16); sw += __shfl_xor(sw, 16);
        sx += __shfl_xor(sx, 32); sy += __shfl_xor(sy, 32);
        sz += __shfl_xor(sz, 32); sw += __shfl_xor(sw, 32);
        if (g == 0) {
            float inv = 1.0f / (float)(deg > 0 ? deg : 1);
            float4 r; r.x = sx * inv; r.y = sy * inv; r.z = sz * inv; r.w = sw * inv;
            *(float4*)(aggr + (size_t)node * DD + gl * 4) = r;
        }
    }
}

// ---------- tri-dense v5: out = agg2@M1.T + agg1@M2.T + x@M3.T + bias ------
// thread = (node, f-half): 2x the waves of thread=node (R12's occupancy cap),
// half the per-wave scalar traffic. 128-node tile staged in stride-65 LDS
// (coalesced global, lane-distinct conflict-free ds_read). Weights via
// scalar s_load (loop-uniform). acc[32] static-indexed -> ~55 VGPR.
// Writeout funnels acc through the reused LDS tile for coalesced stores.
__global__ __launch_bounds__(256)
void tri_dense5(const float* __restrict__ agg2,
                const float* __restrict__ agg1,
                const float* __restrict__ x,
                const float* __restrict__ MT1,
                const float* __restrict__ MT2,
                const float* __restrict__ MT3,
                const float* __restrict__ c0,
                const float* __restrict__ c1,
                const int* __restrict__ rs,
                float* __restrict__ out, int nN)
{
    __shared__ float t_lds[DTILE * 65];
    int tid = threadIdx.x;
    int nl  = tid & 127;         // node within tile
    int fh  = tid >> 7;          // f-half 0/1 (wave-uniform)
    int fbase = fh * 32;
    int base = blockIdx.x * DTILE;
    int node = base + nl;
    int gn = node < nN ? node : nN - 1;

    float ind = (rs[gn + 1] - rs[gn]) > 0 ? 1.0f : 0.0f;
    float acc[32];
#pragma unroll
    for (int j = 0; j < 32; ++j)
        acc[j] = fmaf(ind, c1[fbase + j], c0[fbase + j]);

#define STAGE(SRC)                                                            \
    {                                                                         \
        _Pragma("unroll")                                                     \
        for (int i = 0; i < 8; ++i) {                                         \
            int fi = i * 256 + tid;        /* 0..2047 float4 slots */         \
            int row = fi >> 4;                                                \
            int col = (fi & 15) * 4;                                          \
            int grow = base + row;                                            \
            if (grow >= nN) grow = nN - 1;                                    \
            *(float4*)&t_lds[row * 65 + col] =                                \
                *(const float4*)((SRC) + (size_t)grow * DD + col);            \
        }                                                                     \
    }

#define PHASE(MT)                                                             \
    {                                                                         \
        _Pragma("unroll 1")                                                   \
        for (int k = 0; k < DD; ++k) {                                        \
            float ink = t_lds[nl * 65 + k];                                   \
            const float* mrow = (MT) + k * DD + fbase;                        \
            _Pragma("unroll")                                                 \
            for (int j = 0; j < 32; ++j)                                      \
                acc[j] = fmaf(ink, mrow[j], acc[j]);                          \
        }                                                                     \
    }

    STAGE(agg2);
    __syncthreads();
    PHASE(MT1);
    __syncthreads();
    STAGE(agg1);
    __syncthreads();
    PHASE(MT2);
    __syncthreads();
    STAGE(x);
    __syncthreads();
    PHASE(MT3);
    __syncthreads();

    // funnel acc through LDS (reuse t_lds) for coalesced global stores
#pragma unroll
    for (int j = 0; j < 32; j += 4) {
        float4 o;
        o.x = acc[j]; o.y = acc[j + 1]; o.z = acc[j + 2]; o.w = acc[j + 3];
        *(float4*)&t_lds[nl * 65 + fbase + j] = o;
    }
    __syncthreads();
#pragma unroll
    for (int i = 0; i < 8; ++i) {
        int fi = i * 256 + tid;
        int row = fi >> 4;
        int col = (fi & 15) * 4;
        int grow = base + row;
        if (grow < nN)
            *(float4*)(out + (size_t)grow * DD + col) = *(float4*)&t_lds[row * 65 + col];
    }
#undef STAGE
#undef PHASE
}

extern "C" void kernel_launch(void* const* d_in, const int* in_sizes, int n_in,
                              void* d_out, int out_size, void* d_ws, size_t ws_size,
                              hipStream_t stream)
{
    const float* x   = (const float*)d_in[0];
    const int*   ei  = (const int*)d_in[1];
    const float* W1l = (const float*)d_in[2];
    const float* b1l = (const float*)d_in[3];
    const float* W1r = (const float*)d_in[4];
    const float* W2l = (const float*)d_in[5];
    const float* b2l = (const float*)d_in[6];
    const float* W2r = (const float*)d_in[7];
    float* out = (float*)d_out;

    int nN = in_sizes[0] / DD;   // 100000
    int nE = in_sizes[1] / 2;    // 1600000
    const int* src = ei;
    const int* dst = ei + nE;

    // ws layout (floats):
    // degi[nN] | rs[nN+1] | partials[128] | csr[nE] | pad-to-4 |
    // MT1[4096] | MT2[4096] | MT3[4096] | c0[64] | c1[64] | agg1[nN*DD] | agg2[nN*DD]
    // rank[nE] aliases agg2 (dead before agg2 is born)
    int* degi     = (int*)d_ws;
    int* rs       = degi + nN;
    int* partials = rs + nN + 1;
    int* csr      = partials + 128;
    size_t ofs = (size_t)(nN + nN + 1 + 128 + nE);
    ofs = (ofs + 3) & ~(size_t)3;
    float* MT1 = (float*)d_ws + ofs;
    float* MT2 = MT1 + DD * DD;
    float* MT3 = MT2 + DD * DD;
    float* c0 = MT3 + DD * DD;
    float* c1 = c0 + DD;
    float* agg1 = c1 + DD;
    float* agg2 = agg1 + (size_t)nN * DD;
    int*   rank = (int*)agg2;

    int nblk = (nN + SCAN_T - 1) / SCAN_T;     // 98
    int nden = (nN + DTILE - 1) / DTILE;       // 782

    // 1) histogram + rank
    hipMemsetAsync(degi, 0, sizeof(int) * (size_t)nN, stream);
    hist_kernel<<<2048, 256, 0, stream>>>(dst, degi, rank, nE);
    // 2) exclusive scan -> rs
    scan1_kernel<<<nblk, SCAN_T, 0, stream>>>(degi, rs, partials, nN);
    scan2_kernel<<<1, 64, 0, stream>>>(partials, rs, nblk, nN);
    scan3_kernel<<<nblk, SCAN_T, 0, stream>>>(rs, partials, nN);
    // 3) fill CSR (no atomics)
    fill_kernel<<<2048, 256, 0, stream>>>(src, dst, rs, rank, csr, nE);
    // 4) collapse weights (transposed MT for scalar row loads)
    prep_kernel<<<64, 64, 0, stream>>>(W1l, W1r, W2l, W2r, b1l, b2l,
                                       MT1, MT2, MT3, c0, c1);
    // 5) two aggregations (rank alias now dead; agg2 may be written)
    aggregate_kernel<<<6144, 256, 0, stream>>>(x, csr, rs, agg1, nN);
    aggregate_kernel<<<6144, 256, 0, stream>>>(agg1, csr, rs, agg2, nN);
    // 6) single fused dense pass (thread=(node,f-half), LDS-staged)
    tri_dense5<<<nden, 256, 0, stream>>>(agg2, agg1, x, MT1, MT2, MT3,
                                         c0, c1, rs, out, nN);
}

// Round 14
// 303.863 us; speedup vs baseline: 1.4005x; 1.4005x over previous
//
#include <hip/hip_runtime.h>

#define DD 64
#define SCAN_T 1024
#define DTILE 128

// ---------- CSR build ----------

// histogram + per-edge rank within its dst (rank = atomic return value)
__global__ __launch_bounds__(256)
void hist_kernel(const int* __restrict__ dst, int* __restrict__ degi,
                 int* __restrict__ rank, int nE)
{
    for (int e = blockIdx.x * blockDim.x + threadIdx.x; e < nE;
         e += gridDim.x * blockDim.x) {
        int r = atomicAdd(&degi[dst[e]], 1);
        rank[e] = r;
    }
}

__global__ __launch_bounds__(SCAN_T)
void scan1_kernel(const int* __restrict__ degi, int* __restrict__ rs,
                  int* __restrict__ partials, int nN)
{
    __shared__ int s[SCAN_T];
    int tid = threadIdx.x;
    int gid = blockIdx.x * SCAN_T + tid;
    int v = (gid < nN) ? degi[gid] : 0;
    s[tid] = v;
    __syncthreads();
    for (int off = 1; off < SCAN_T; off <<= 1) {
        int t = (tid >= off) ? s[tid - off] : 0;
        __syncthreads();
        s[tid] += t;
        __syncthreads();
    }
    if (gid < nN) rs[gid] = s[tid] - v;   // exclusive
    if (tid == SCAN_T - 1) partials[blockIdx.x] = s[SCAN_T - 1];
}

// wave-parallel exclusive scan over <=128 block partials
__global__ void scan2_kernel(int* __restrict__ partials, int* __restrict__ rs,
                             int nblk, int nN)
{
    int lane = threadIdx.x;   // 64 threads
    int p0 = (lane < nblk) ? partials[lane] : 0;
    int p1 = (64 + lane < nblk) ? partials[64 + lane] : 0;
    int v0 = p0;
    for (int off = 1; off < 64; off <<= 1) {
        int t = __shfl_up(v0, off);
        if (lane >= off) v0 += t;
    }
    int total0 = __shfl(v0, 63);
    int v1 = p1;
    for (int off = 1; off < 64; off <<= 1) {
        int t = __shfl_up(v1, off);
        if (lane >= off) v1 += t;
    }
    int grand = total0 + __shfl(v1, 63);
    if (lane < nblk) partials[lane] = v0 - p0;
    if (64 + lane < nblk) partials[64 + lane] = total0 + v1 - p1;
    if (lane == 0) rs[nN] = grand;   // == nE
}

__global__ __launch_bounds__(SCAN_T)
void scan3_kernel(int* __restrict__ rs, const int* __restrict__ partials, int nN)
{
    int gid = blockIdx.x * SCAN_T + threadIdx.x;
    if (gid < nN) rs[gid] += partials[blockIdx.x];
}

// scatter src into CSR slot rs[d]+rank[e] — NO atomics
__global__ __launch_bounds__(256)
void fill_kernel(const int* __restrict__ src, const int* __restrict__ dst,
                 const int* __restrict__ rs, const int* __restrict__ rank,
                 int* __restrict__ csr, int nE)
{
    for (int e = blockIdx.x * blockDim.x + threadIdx.x; e < nE;
         e += gridDim.x * blockDim.x) {
        csr[rs[dst[e]] + rank[e]] = src[e];
    }
}

// ---------- weight precompute: collapse the two layers ----------
// MT1 = (W2l*W1l)^T ; MT2 = (W2l*W1r + W2r*W1l)^T ; MT3 = (W2r*W1r)^T
// stored TRANSPOSED: MT[k*DD+f] so the dense kernel's per-k scalar row
// loads are contiguous. c1 = b1 @ W2l.T ; c0 = b1 @ W2r.T + b2
// out = agg2@M1.T + agg1@M2.T + x@M3.T + ind*c1 + c0
__global__ void prep_kernel(const float* __restrict__ W1l,
                            const float* __restrict__ W1r,
                            const float* __restrict__ W2l,
                            const float* __restrict__ W2r,
                            const float* __restrict__ b1,
                            const float* __restrict__ b2,
                            float* __restrict__ MT1, float* __restrict__ MT2,
                            float* __restrict__ MT3, float* __restrict__ c0,
                            float* __restrict__ c1)
{
    int f = blockIdx.x;      // 64 blocks
    int k = threadIdx.x;     // 64 threads
    float m1 = 0.f, m2 = 0.f, m3 = 0.f;
    for (int j = 0; j < DD; ++j) {
        float a2l = W2l[f * DD + j];
        float a2r = W2r[f * DD + j];
        float w1l = W1l[j * DD + k];
        float w1r = W1r[j * DD + k];
        m1 = fmaf(a2l, w1l, m1);
        m2 = fmaf(a2l, w1r, m2);
        m2 = fmaf(a2r, w1l, m2);
        m3 = fmaf(a2r, w1r, m3);
    }
    MT1[k * DD + f] = m1;
    MT2[k * DD + f] = m2;
    MT3[k * DD + f] = m3;
    float t1 = W2l[f * DD + k] * b1[k];
    float t0 = W2r[f * DD + k] * b1[k];
    for (int off = 1; off < 64; off <<= 1) {
        t1 += __shfl_xor(t1, off);
        t0 += __shfl_xor(t0, off);
    }
    if (k == 0) {
        c1[f] = t1;
        c0[f] = t0 + b2[f];
    }
}

// ---------- aggregation: mean over neighbors ----------
// Wave per node; 16-lane group g takes rows {j+g, j+4+g, ..., j+28+g}:
// EIGHT independent float4 gathers in flight per step. Branch-free.
__global__ __launch_bounds__(256, 4)
void aggregate_kernel(const float* __restrict__ xin,
                      const int* __restrict__ csr,
                      const int* __restrict__ rs,
                      float* __restrict__ aggr, int nN)
{
    int lane = threadIdx.x & 63;
    int w = threadIdx.x >> 6;
    int g  = lane >> 4;        // group 0..3
    int gl = lane & 15;        // lane within group
    int totWaves = gridDim.x * 4;
    for (int node = blockIdx.x * 4 + w; node < nN; node += totWaves) {
        int beg = rs[node], end = rs[node + 1];
        int deg = end - beg;
        float4 a0 = {0,0,0,0}, a1 = {0,0,0,0}, a2 = {0,0,0,0}, a3 = {0,0,0,0};
        float4 a4 = {0,0,0,0}, a5 = {0,0,0,0}, a6 = {0,0,0,0}, a7 = {0,0,0,0};
        for (int base = beg; base < end; base += 64) {
            int n = end - base;
            if (n > 64) n = 64;
            // lanes >= n read csr[base] (valid, hot) so shfl'd idx are safe
            int myIdx = csr[(lane < n) ? (base + lane) : base];
            for (int j = 0; j < n; j += 32) {
#define GSLOT(ACC, OFS)                                                       \
                {                                                             \
                    int ii = j + (OFS) + g;                                   \
                    int si = __shfl(myIdx, ii & 63);                          \
                    float mm = (ii < n) ? 1.f : 0.f;                          \
                    float4 v = *(const float4*)(xin + (size_t)si * DD + gl * 4);\
                    ACC.x = fmaf(mm, v.x, ACC.x);                             \
                    ACC.y = fmaf(mm, v.y, ACC.y);                             \
                    ACC.z = fmaf(mm, v.z, ACC.z);                             \
                    ACC.w = fmaf(mm, v.w, ACC.w);                             \
                }
                GSLOT(a0, 0)  GSLOT(a1, 4)  GSLOT(a2, 8)  GSLOT(a3, 12)
                GSLOT(a4, 16) GSLOT(a5, 20) GSLOT(a6, 24) GSLOT(a7, 28)
#undef GSLOT
            }
        }
        float sx = ((a0.x + a1.x) + (a2.x + a3.x)) + ((a4.x + a5.x) + (a6.x + a7.x));
        float sy = ((a0.y + a1.y) + (a2.y + a3.y)) + ((a4.y + a5.y) + (a6.y + a7.y));
        float sz = ((a0.z + a1.z) + (a2.z + a3.z)) + ((a4.z + a5.z) + (a6.z + a7.z));
        float sw = ((a0.w + a1.w) + (a2.w + a3.w)) + ((a4.w + a5.w) + (a6.w + a7.w));
        sx += __shfl_xor(sx, 16); sy += __shfl_xor(sy, 16);
        sz += __shfl_xor(sz, 16); sw += __shfl_xor(sw, 16);
        sx += __shfl_xor(sx, 32); sy += __shfl_xor(sy, 32);
        sz += __shfl_xor(sz, 32); sw += __shfl_xor(sw, 32);
        if (g == 0) {
            float inv = 1.0f / (float)(deg > 0 ? deg : 1);
            float4 r; r.x = sx * inv; r.y = sy * inv; r.z = sz * inv; r.w = sw * inv;
            *(float4*)(aggr + (size_t)node * DD + gl * 4) = r;
        }
    }
}

// ---------- tri-dense v5b: out = agg2@M1.T + agg1@M2.T + x@M3.T + bias -----
// thread = (node, f-half). R13 failure root-caused: fbase=(tid>>7)*32 is
// wave-uniform IN FACT but not PROVABLY so -> weight loads became per-lane
// vector broadcasts instead of s_load. readfirstlane forces the scalar path,
// keeping the 2x wave parallelism AND the scalar-pipe weight loads.
__global__ __launch_bounds__(256)
void tri_dense5(const float* __restrict__ agg2,
                const float* __restrict__ agg1,
                const float* __restrict__ x,
                const float* __restrict__ MT1,
                const float* __restrict__ MT2,
                const float* __restrict__ MT3,
                const float* __restrict__ c0,
                const float* __restrict__ c1,
                const int* __restrict__ rs,
                float* __restrict__ out, int nN)
{
    __shared__ float t_lds[DTILE * 65];
    int tid = threadIdx.x;
    int nl  = tid & 127;         // node within tile
    // f-half 0/1 — wave-uniform; FORCE scalar so weight addrs ride s_load
    int fbase = __builtin_amdgcn_readfirstlane((tid >> 7) * 32);
    int base = blockIdx.x * DTILE;
    int node = base + nl;
    int gn = node < nN ? node : nN - 1;

    float ind = (rs[gn + 1] - rs[gn]) > 0 ? 1.0f : 0.0f;
    float acc[32];
#pragma unroll
    for (int j = 0; j < 32; ++j)
        acc[j] = fmaf(ind, c1[fbase + j], c0[fbase + j]);

#define STAGE(SRC)                                                            \
    {                                                                         \
        _Pragma("unroll")                                                     \
        for (int i = 0; i < 8; ++i) {                                         \
            int fi = i * 256 + tid;        /* 0..2047 float4 slots */         \
            int row = fi >> 4;                                                \
            int col = (fi & 15) * 4;                                          \
            int grow = base + row;                                            \
            if (grow >= nN) grow = nN - 1;                                    \
            *(float4*)&t_lds[row * 65 + col] =                                \
                *(const float4*)((SRC) + (size_t)grow * DD + col);            \
        }                                                                     \
    }

#define PHASE(MT)                                                             \
    {                                                                         \
        _Pragma("unroll 1")                                                   \
        for (int k = 0; k < DD; ++k) {                                        \
            float ink = t_lds[nl * 65 + k];                                   \
            const float* mrow = (MT) + k * DD + fbase;                        \
            _Pragma("unroll")                                                 \
            for (int j = 0; j < 32; ++j)                                      \
                acc[j] = fmaf(ink, mrow[j], acc[j]);                          \
        }                                                                     \
    }

    STAGE(agg2);
    __syncthreads();
    PHASE(MT1);
    __syncthreads();
    STAGE(agg1);
    __syncthreads();
    PHASE(MT2);
    __syncthreads();
    STAGE(x);
    __syncthreads();
    PHASE(MT3);
    __syncthreads();

    // funnel acc through LDS (reuse t_lds) for coalesced global stores
#pragma unroll
    for (int j = 0; j < 32; j += 4) {
        float4 o;
        o.x = acc[j]; o.y = acc[j + 1]; o.z = acc[j + 2]; o.w = acc[j + 3];
        *(float4*)&t_lds[nl * 65 + fbase + j] = o;
    }
    __syncthreads();
#pragma unroll
    for (int i = 0; i < 8; ++i) {
        int fi = i * 256 + tid;
        int row = fi >> 4;
        int col = (fi & 15) * 4;
        int grow = base + row;
        if (grow < nN)
            *(float4*)(out + (size_t)grow * DD + col) = *(float4*)&t_lds[row * 65 + col];
    }
#undef STAGE
#undef PHASE
}

extern "C" void kernel_launch(void* const* d_in, const int* in_sizes, int n_in,
                              void* d_out, int out_size, void* d_ws, size_t ws_size,
                              hipStream_t stream)
{
    const float* x   = (const float*)d_in[0];
    const int*   ei  = (const int*)d_in[1];
    const float* W1l = (const float*)d_in[2];
    const float* b1l = (const float*)d_in[3];
    const float* W1r = (const float*)d_in[4];
    const float* W2l = (const float*)d_in[5];
    const float* b2l = (const float*)d_in[6];
    const float* W2r = (const float*)d_in[7];
    float* out = (float*)d_out;

    int nN = in_sizes[0] / DD;   // 100000
    int nE = in_sizes[1] / 2;    // 1600000
    const int* src = ei;
    const int* dst = ei + nE;

    // ws layout (floats):
    // degi[nN] | rs[nN+1] | partials[128] | csr[nE] | pad-to-4 |
    // MT1[4096] | MT2[4096] | MT3[4096] | c0[64] | c1[64] | agg1[nN*DD] | agg2[nN*DD]
    // rank[nE] aliases agg2 (dead before agg2 is born)
    int* degi     = (int*)d_ws;
    int* rs       = degi + nN;
    int* partials = rs + nN + 1;
    int* csr      = partials + 128;
    size_t ofs = (size_t)(nN + nN + 1 + 128 + nE);
    ofs = (ofs + 3) & ~(size_t)3;
    float* MT1 = (float*)d_ws + ofs;
    float* MT2 = MT1 + DD * DD;
    float* MT3 = MT2 + DD * DD;
    float* c0 = MT3 + DD * DD;
    float* c1 = c0 + DD;
    float* agg1 = c1 + DD;
    float* agg2 = agg1 + (size_t)nN * DD;
    int*   rank = (int*)agg2;

    int nblk = (nN + SCAN_T - 1) / SCAN_T;     // 98
    int nden = (nN + DTILE - 1) / DTILE;       // 782

    // 1) histogram + rank
    hipMemsetAsync(degi, 0, sizeof(int) * (size_t)nN, stream);
    hist_kernel<<<2048, 256, 0, stream>>>(dst, degi, rank, nE);
    // 2) exclusive scan -> rs
    scan1_kernel<<<nblk, SCAN_T, 0, stream>>>(degi, rs, partials, nN);
    scan2_kernel<<<1, 64, 0, stream>>>(partials, rs, nblk, nN);
    scan3_kernel<<<nblk, SCAN_T, 0, stream>>>(rs, partials, nN);
    // 3) fill CSR (no atomics)
    fill_kernel<<<2048, 256, 0, stream>>>(src, dst, rs, rank, csr, nE);
    // 4) collapse weights (transposed MT for scalar row loads)
    prep_kernel<<<64, 64, 0, stream>>>(W1l, W1r, W2l, W2r, b1l, b2l,
                                       MT1, MT2, MT3, c0, c1);
    // 5) two aggregations (rank alias now dead; agg2 may be written)
    aggregate_kernel<<<6144, 256, 0, stream>>>(x, csr, rs, agg1, nN);
    aggregate_kernel<<<6144, 256, 0, stream>>>(agg1, csr, rs, agg2, nN);
    // 6) single fused dense pass (thread=(node,f-half), scalar weights forced)
    tri_dense5<<<nden, 256, 0, stream>>>(agg2, agg1, x, MT1, MT2, MT3,
                                         c0, c1, rs, out, nN);
}

// Round 15
// 281.685 us; speedup vs baseline: 1.5108x; 1.0787x over previous
//
#include <hip/hip_runtime.h>

#define DD 64
#define SCAN_T 1024
#define DTILE 128

typedef unsigned short ushort_t;

static __device__ __forceinline__ unsigned short f2bf(float f)
{
    unsigned u = __float_as_uint(f);
    unsigned r = (u + 0x7FFFu + ((u >> 16) & 1u)) >> 16;   // round-nearest-even
    return (unsigned short)r;
}
static __device__ __forceinline__ float bf_lo(unsigned w) { return __uint_as_float(w << 16); }
static __device__ __forceinline__ float bf_hi(unsigned w) { return __uint_as_float(w & 0xFFFF0000u); }

// ---------- CSR build ----------

// histogram + per-edge rank within its dst (rank = atomic return value)
__global__ __launch_bounds__(256)
void hist_kernel(const int* __restrict__ dst, int* __restrict__ degi,
                 int* __restrict__ rank, int nE)
{
    for (int e = blockIdx.x * blockDim.x + threadIdx.x; e < nE;
         e += gridDim.x * blockDim.x) {
        int r = atomicAdd(&degi[dst[e]], 1);
        rank[e] = r;
    }
}

__global__ __launch_bounds__(SCAN_T)
void scan1_kernel(const int* __restrict__ degi, int* __restrict__ rs,
                  int* __restrict__ partials, int nN)
{
    __shared__ int s[SCAN_T];
    int tid = threadIdx.x;
    int gid = blockIdx.x * SCAN_T + tid;
    int v = (gid < nN) ? degi[gid] : 0;
    s[tid] = v;
    __syncthreads();
    for (int off = 1; off < SCAN_T; off <<= 1) {
        int t = (tid >= off) ? s[tid - off] : 0;
        __syncthreads();
        s[tid] += t;
        __syncthreads();
    }
    if (gid < nN) rs[gid] = s[tid] - v;   // exclusive
    if (tid == SCAN_T - 1) partials[blockIdx.x] = s[SCAN_T - 1];
}

// wave-parallel exclusive scan over <=128 block partials
__global__ void scan2_kernel(int* __restrict__ partials, int* __restrict__ rs,
                             int nblk, int nN)
{
    int lane = threadIdx.x;   // 64 threads
    int p0 = (lane < nblk) ? partials[lane] : 0;
    int p1 = (64 + lane < nblk) ? partials[64 + lane] : 0;
    int v0 = p0;
    for (int off = 1; off < 64; off <<= 1) {
        int t = __shfl_up(v0, off);
        if (lane >= off) v0 += t;
    }
    int total0 = __shfl(v0, 63);
    int v1 = p1;
    for (int off = 1; off < 64; off <<= 1) {
        int t = __shfl_up(v1, off);
        if (lane >= off) v1 += t;
    }
    int grand = total0 + __shfl(v1, 63);
    if (lane < nblk) partials[lane] = v0 - p0;
    if (64 + lane < nblk) partials[64 + lane] = total0 + v1 - p1;
    if (lane == 0) rs[nN] = grand;   // == nE
}

__global__ __launch_bounds__(SCAN_T)
void scan3_kernel(int* __restrict__ rs, const int* __restrict__ partials, int nN)
{
    int gid = blockIdx.x * SCAN_T + threadIdx.x;
    if (gid < nN) rs[gid] += partials[blockIdx.x];
}

// scatter src into CSR slot rs[d]+rank[e] — NO atomics
__global__ __launch_bounds__(256)
void fill_kernel(const int* __restrict__ src, const int* __restrict__ dst,
                 const int* __restrict__ rs, const int* __restrict__ rank,
                 int* __restrict__ csr, int nE)
{
    for (int e = blockIdx.x * blockDim.x + threadIdx.x; e < nE;
         e += gridDim.x * blockDim.x) {
        csr[rs[dst[e]] + rank[e]] = src[e];
    }
}

// ---------- fp32 -> bf16 conversion (8 elems/thread) ----------
__global__ __launch_bounds__(256)
void tobf16_kernel(const float* __restrict__ in, ushort_t* __restrict__ outh,
                   int nTot8)
{
    int i = blockIdx.x * 256 + threadIdx.x;
    if (i >= nTot8) return;
    float4 v0 = *(const float4*)(in + (size_t)i * 8);
    float4 v1 = *(const float4*)(in + (size_t)i * 8 + 4);
    uint4 o;
    o.x = (unsigned)f2bf(v0.x) | ((unsigned)f2bf(v0.y) << 16);
    o.y = (unsigned)f2bf(v0.z) | ((unsigned)f2bf(v0.w) << 16);
    o.z = (unsigned)f2bf(v1.x) | ((unsigned)f2bf(v1.y) << 16);
    o.w = (unsigned)f2bf(v1.z) | ((unsigned)f2bf(v1.w) << 16);
    *(uint4*)(outh + (size_t)i * 8) = o;
}

// ---------- weight precompute: collapse the two layers ----------
// MT1 = (W2l*W1l)^T ; MT2 = (W2l*W1r + W2r*W1l)^T ; MT3 = (W2r*W1r)^T
// stored TRANSPOSED (MT[k*DD+f]) for contiguous scalar row loads.
// c1 = b1 @ W2l.T ; c0 = b1 @ W2r.T + b2
__global__ void prep_kernel(const float* __restrict__ W1l,
                            const float* __restrict__ W1r,
                            const float* __restrict__ W2l,
                            const float* __restrict__ W2r,
                            const float* __restrict__ b1,
                            const float* __restrict__ b2,
                            float* __restrict__ MT1, float* __restrict__ MT2,
                            float* __restrict__ MT3, float* __restrict__ c0,
                            float* __restrict__ c1)
{
    int f = blockIdx.x;      // 64 blocks
    int k = threadIdx.x;     // 64 threads
    float m1 = 0.f, m2 = 0.f, m3 = 0.f;
    for (int j = 0; j < DD; ++j) {
        float a2l = W2l[f * DD + j];
        float a2r = W2r[f * DD + j];
        float w1l = W1l[j * DD + k];
        float w1r = W1r[j * DD + k];
        m1 = fmaf(a2l, w1l, m1);
        m2 = fmaf(a2l, w1r, m2);
        m2 = fmaf(a2r, w1l, m2);
        m3 = fmaf(a2r, w1r, m3);
    }
    MT1[k * DD + f] = m1;
    MT2[k * DD + f] = m2;
    MT3[k * DD + f] = m3;
    float t1 = W2l[f * DD + k] * b1[k];
    float t0 = W2r[f * DD + k] * b1[k];
    for (int off = 1; off < 64; off <<= 1) {
        t1 += __shfl_xor(t1, off);
        t0 += __shfl_xor(t0, off);
    }
    if (k == 0) {
        c1[f] = t1;
        c0[f] = t0 + b2[f];
    }
}

// ---------- aggregation over bf16 rows: mean over neighbors ----------
// Rows are 128B (64 bf16). 8-lane group g handles a row with uint4 (16B/lane)
// loads. 4 independent slots per j-step: 32 rows in flight per wave at HALF
// the bytes of the fp32 version (R14 evidence: byte-throughput-bound).
// fp32 accumulation; bf16 RNE output (halves write traffic + next gather).
__global__ __launch_bounds__(256, 4)
void aggregate_bf16(const ushort_t* __restrict__ xh,
                    const int* __restrict__ csr,
                    const int* __restrict__ rs,
                    ushort_t* __restrict__ aggrh, int nN)
{
    int lane = threadIdx.x & 63;
    int w = threadIdx.x >> 6;
    int g  = lane >> 3;        // group 0..7
    int gl = lane & 7;         // lane within group
    int totWaves = gridDim.x * 4;
    for (int node = blockIdx.x * 4 + w; node < nN; node += totWaves) {
        int beg = rs[node], end = rs[node + 1];
        int deg = end - beg;
        float4 l0 = {0,0,0,0}, h0 = {0,0,0,0};
        float4 l1 = {0,0,0,0}, h1 = {0,0,0,0};
        float4 l2 = {0,0,0,0}, h2 = {0,0,0,0};
        float4 l3 = {0,0,0,0}, h3 = {0,0,0,0};
        for (int base = beg; base < end; base += 64) {
            int n = end - base;
            if (n > 64) n = 64;
            int myIdx = csr[(lane < n) ? (base + lane) : base];
            for (int j = 0; j < n; j += 32) {
#define GSLOT(LO, HI, OFS)                                                    \
                {                                                             \
                    int ii = j + (OFS) + g;                                   \
                    int si = __shfl(myIdx, ii & 63);                          \
                    float mm = (ii < n) ? 1.f : 0.f;                          \
                    uint4 v = *(const uint4*)(xh + (size_t)si * DD + gl * 8); \
                    LO.x = fmaf(mm, bf_lo(v.x), LO.x);                        \
                    LO.y = fmaf(mm, bf_hi(v.x), LO.y);                        \
                    LO.z = fmaf(mm, bf_lo(v.y), LO.z);                        \
                    LO.w = fmaf(mm, bf_hi(v.y), LO.w);                        \
                    HI.x = fmaf(mm, bf_lo(v.z), HI.x);                        \
                    HI.y = fmaf(mm, bf_hi(v.z), HI.y);                        \
                    HI.z = fmaf(mm, bf_lo(v.w), HI.z);                        \
                    HI.w = fmaf(mm, bf_hi(v.w), HI.w);                        \
                }
                GSLOT(l0, h0, 0)  GSLOT(l1, h1, 8)
                GSLOT(l2, h2, 16) GSLOT(l3, h3, 24)
#undef GSLOT
            }
        }
        float4 lo, hi;
        lo.x = (l0.x + l1.x) + (l2.x + l3.x);
        lo.y = (l0.y + l1.y) + (l2.y + l3.y);
        lo.z = (l0.z + l1.z) + (l2.z + l3.z);
        lo.w = (l0.w + l1.w) + (l2.w + l3.w);
        hi.x = (h0.x + h1.x) + (h2.x + h3.x);
        hi.y = (h0.y + h1.y) + (h2.y + h3.y);
        hi.z = (h0.z + h1.z) + (h2.z + h3.z);
        hi.w = (h0.w + h1.w) + (h2.w + h3.w);
        // reduce across the 8 groups (lane bits 3,4,5)
#pragma unroll
        for (int m = 8; m <= 32; m <<= 1) {
            lo.x += __shfl_xor(lo.x, m); lo.y += __shfl_xor(lo.y, m);
            lo.z += __shfl_xor(lo.z, m); lo.w += __shfl_xor(lo.w, m);
            hi.x += __shfl_xor(hi.x, m); hi.y += __shfl_xor(hi.y, m);
            hi.z += __shfl_xor(hi.z, m); hi.w += __shfl_xor(hi.w, m);
        }
        if (g == 0) {
            float inv = 1.0f / (float)(deg > 0 ? deg : 1);
            uint4 o;
            o.x = (unsigned)f2bf(lo.x * inv) | ((unsigned)f2bf(lo.y * inv) << 16);
            o.y = (unsigned)f2bf(lo.z * inv) | ((unsigned)f2bf(lo.w * inv) << 16);
            o.z = (unsigned)f2bf(hi.x * inv) | ((unsigned)f2bf(hi.y * inv) << 16);
            o.w = (unsigned)f2bf(hi.z * inv) | ((unsigned)f2bf(hi.w * inv) << 16);
            *(uint4*)(aggrh + (size_t)node * DD + gl * 8) = o;
        }
    }
}

// ---------- tri-dense: out = agg2@M1.T + agg1@M2.T + x@M3.T + bias ---------
// thread = (node, f-half); bf16 inputs staged+unpacked into fp32 LDS tile;
// weights fp32 via forced-scalar s_load (readfirstlane on fbase).
__global__ __launch_bounds__(256)
void tri_dense5(const ushort_t* __restrict__ agg2h,
                const ushort_t* __restrict__ agg1h,
                const ushort_t* __restrict__ xh,
                const float* __restrict__ MT1,
                const float* __restrict__ MT2,
                const float* __restrict__ MT3,
                const float* __restrict__ c0,
                const float* __restrict__ c1,
                const int* __restrict__ rs,
                float* __restrict__ out, int nN)
{
    __shared__ float t_lds[DTILE * 65];
    int tid = threadIdx.x;
    int nl  = tid & 127;         // node within tile
    // f-half 0/1 — wave-uniform; FORCE scalar so weight addrs ride s_load
    int fbase = __builtin_amdgcn_readfirstlane((tid >> 7) * 32);
    int base = blockIdx.x * DTILE;
    int node = base + nl;
    int gn = node < nN ? node : nN - 1;

    float ind = (rs[gn + 1] - rs[gn]) > 0 ? 1.0f : 0.0f;
    float acc[32];
#pragma unroll
    for (int j = 0; j < 32; ++j)
        acc[j] = fmaf(ind, c1[fbase + j], c0[fbase + j]);

#define STAGE(SRCH)                                                           \
    {                                                                         \
        _Pragma("unroll")                                                     \
        for (int i = 0; i < 4; ++i) {                                         \
            int fi = i * 256 + tid;        /* 0..1023 uint4 slots */          \
            int row = fi >> 3;                                                \
            int col = (fi & 7) * 8;                                           \
            int grow = base + row;                                            \
            if (grow >= nN) grow = nN - 1;                                    \
            uint4 v = *(const uint4*)((SRCH) + (size_t)grow * DD + col);      \
            float4 lo, hi;                                                    \
            lo.x = bf_lo(v.x); lo.y = bf_hi(v.x);                             \
            lo.z = bf_lo(v.y); lo.w = bf_hi(v.y);                             \
            hi.x = bf_lo(v.z); hi.y = bf_hi(v.z);                             \
            hi.z = bf_lo(v.w); hi.w = bf_hi(v.w);                             \
            *(float4*)&t_lds[row * 65 + col] = lo;                            \
            *(float4*)&t_lds[row * 65 + col + 4] = hi;                        \
        }                                                                     \
    }

#define PHASE(MT)                                                             \
    {                                                                         \
        _Pragma("unroll 1")                                                   \
        for (int k = 0; k < DD; ++k) {                                        \
            float ink = t_lds[nl * 65 + k];                                   \
            const float* mrow = (MT) + k * DD + fbase;                        \
            _Pragma("unroll")                                                 \
            for (int j = 0; j < 32; ++j)                                      \
                acc[j] = fmaf(ink, mrow[j], acc[j]);                          \
        }                                                                     \
    }

    STAGE(agg2h);
    __syncthreads();
    PHASE(MT1);
    __syncthreads();
    STAGE(agg1h);
    __syncthreads();
    PHASE(MT2);
    __syncthreads();
    STAGE(xh);
    __syncthreads();
    PHASE(MT3);
    __syncthreads();

    // funnel acc through LDS (reuse t_lds) for coalesced global stores
#pragma unroll
    for (int j = 0; j < 32; j += 4) {
        float4 o;
        o.x = acc[j]; o.y = acc[j + 1]; o.z = acc[j + 2]; o.w = acc[j + 3];
        *(float4*)&t_lds[nl * 65 + fbase + j] = o;
    }
    __syncthreads();
#pragma unroll
    for (int i = 0; i < 8; ++i) {
        int fi = i * 256 + tid;
        int row = fi >> 4;
        int col = (fi & 15) * 4;
        int grow = base + row;
        if (grow < nN)
            *(float4*)(out + (size_t)grow * DD + col) = *(float4*)&t_lds[row * 65 + col];
    }
#undef STAGE
#undef PHASE
}

extern "C" void kernel_launch(void* const* d_in, const int* in_sizes, int n_in,
                              void* d_out, int out_size, void* d_ws, size_t ws_size,
                              hipStream_t stream)
{
    const float* x   = (const float*)d_in[0];
    const int*   ei  = (const int*)d_in[1];
    const float* W1l = (const float*)d_in[2];
    const float* b1l = (const float*)d_in[3];
    const float* W1r = (const float*)d_in[4];
    const float* W2l = (const float*)d_in[5];
    const float* b2l = (const float*)d_in[6];
    const float* W2r = (const float*)d_in[7];
    float* out = (float*)d_out;

    int nN = in_sizes[0] / DD;   // 100000
    int nE = in_sizes[1] / 2;    // 1600000
    const int* src = ei;
    const int* dst = ei + nE;

    // ws layout (float-sized slots):
    // degi[nN] | rs[nN+1] | partials[128] | csr[nE] | pad |
    // MT1[4096] | MT2[4096] | MT3[4096] | c0[64] | c1[64] |
    // xh[nN*32] | agg1h[nN*32] | agg2h[nN*32]   (bf16 buffers, 12.8MB each)
    // rank[nE] aliases agg2h (dead before agg2h is born)
    int* degi     = (int*)d_ws;
    int* rs       = degi + nN;
    int* partials = rs + nN + 1;
    int* csr      = partials + 128;
    size_t ofs = (size_t)(nN + nN + 1 + 128 + nE);
    ofs = (ofs + 3) & ~(size_t)3;
    float* MT1 = (float*)d_ws + ofs;
    float* MT2 = MT1 + DD * DD;
    float* MT3 = MT2 + DD * DD;
    float* c0 = MT3 + DD * DD;
    float* c1 = c0 + DD;
    float* xh_f    = c1 + DD;
    float* agg1h_f = xh_f + (size_t)nN * 32;
    float* agg2h_f = agg1h_f + (size_t)nN * 32;
    ushort_t* xh    = (ushort_t*)xh_f;
    ushort_t* agg1h = (ushort_t*)agg1h_f;
    ushort_t* agg2h = (ushort_t*)agg2h_f;
    int* rank = (int*)agg2h_f;

    int nblk = (nN + SCAN_T - 1) / SCAN_T;     // 98
    int nden = (nN + DTILE - 1) / DTILE;       // 782
    int ncv  = (nN * 32 / 4 + 255) / 256;      // tobf16 blocks (nN*64/8 threads)

    // 1) histogram + rank
    hipMemsetAsync(degi, 0, sizeof(int) * (size_t)nN, stream);
    hist_kernel<<<2048, 256, 0, stream>>>(dst, degi, rank, nE);
    // 2) exclusive scan -> rs
    scan1_kernel<<<nblk, SCAN_T, 0, stream>>>(degi, rs, partials, nN);
    scan2_kernel<<<1, 64, 0, stream>>>(partials, rs, nblk, nN);
    scan3_kernel<<<nblk, SCAN_T, 0, stream>>>(rs, partials, nN);
    // 3) fill CSR (no atomics)
    fill_kernel<<<2048, 256, 0, stream>>>(src, dst, rs, rank, csr, nE);
    // 4) collapse weights + convert x to bf16
    prep_kernel<<<64, 64, 0, stream>>>(W1l, W1r, W2l, W2r, b1l, b2l,
                                       MT1, MT2, MT3, c0, c1);
    tobf16_kernel<<<ncv, 256, 0, stream>>>(x, xh, nN * DD / 8);
    // 5) two bf16 aggregations (rank alias dead after fill)
    aggregate_bf16<<<6144, 256, 0, stream>>>(xh, csr, rs, agg1h, nN);
    aggregate_bf16<<<6144, 256, 0, stream>>>(agg1h, csr, rs, agg2h, nN);
    // 6) single fused dense pass (bf16 inputs, fp32 math/output)
    tri_dense5<<<nden, 256, 0, stream>>>(agg2h, agg1h, xh, MT1, MT2, MT3,
                                         c0, c1, rs, out, nN);
}

// Round 16
// 209.638 us; speedup vs baseline: 2.0300x; 1.3437x over previous
//
#include <hip/hip_runtime.h>

#define DD 64
#define DTILE 128
#define BSHIFT 7                 // 128 nodes per bucket
#define NBUCK_MAX 800
#define SEGCAP 4096

typedef unsigned short ushort_t;

static __device__ __forceinline__ unsigned short f2bf(float f)
{
    unsigned u = __float_as_uint(f);
    unsigned r = (u + 0x7FFFu + ((u >> 16) & 1u)) >> 16;   // round-nearest-even
    return (unsigned short)r;
}
static __device__ __forceinline__ float bf_lo(unsigned w) { return __uint_as_float(w << 16); }
static __device__ __forceinline__ float bf_hi(unsigned w) { return __uint_as_float(w & 0xFFFF0000u); }

// ================= bucketed CSR build (no global atomics) =================
// R15 evidence: random-grain global RMW (hist/fill atomics) runs ~1 TB/s;
// this pipeline makes every global access a coalesced stream.

// A: per-block LDS bucket histogram -> partialCnt[bucket*256+blk]
__global__ __launch_bounds__(256)
void bucket_count(const int* __restrict__ dst, int* __restrict__ partialCnt,
                  int nE, int chunk, int nbuck)
{
    __shared__ int bins[NBUCK_MAX];
    int blk = blockIdx.x, t = threadIdx.x;
    for (int i = t; i < nbuck; i += 256) bins[i] = 0;
    __syncthreads();
    int e0 = blk * chunk;
    int e1 = e0 + chunk; if (e1 > nE) e1 = nE;
    for (int e = e0 + t; e < e1; e += 256)
        atomicAdd(&bins[dst[e] >> BSHIFT], 1);
    __syncthreads();
    for (int i = t; i < nbuck; i += 256)
        partialCnt[(size_t)i * 256 + blk] = bins[i];
}

// A2: per-bucket exclusive scan over its 256 block counts; total -> bucketTot
__global__ __launch_bounds__(256)
void bucket_scanblocks(int* __restrict__ partialCnt, int* __restrict__ bucketTot)
{
    __shared__ int s[256];
    int b = blockIdx.x, t = threadIdx.x;
    int v = partialCnt[(size_t)b * 256 + t];
    s[t] = v;
    __syncthreads();
    for (int off = 1; off < 256; off <<= 1) {
        int u = (t >= off) ? s[t - off] : 0;
        __syncthreads();
        s[t] += u;
        __syncthreads();
    }
    partialCnt[(size_t)b * 256 + t] = s[t] - v;   // exclusive
    if (t == 255) bucketTot[b] = s[255];
}

// A3: exclusive scan over bucket totals -> bucketBase; also rs[nN]=nE
__global__ __launch_bounds__(1024)
void bucket_scanbase(const int* __restrict__ bucketTot, int* __restrict__ bucketBase,
                     int* __restrict__ rs, int nbuck, int nN)
{
    __shared__ int s[1024];
    int t = threadIdx.x;
    int v = (t < nbuck) ? bucketTot[t] : 0;
    s[t] = v;
    __syncthreads();
    for (int off = 1; off < 1024; off <<= 1) {
        int u = (t >= off) ? s[t - off] : 0;
        __syncthreads();
        s[t] += u;
        __syncthreads();
    }
    if (t < nbuck) bucketBase[t] = s[t] - v;
    if (t == nbuck - 1) {
        bucketBase[nbuck] = s[t];
        rs[nN] = s[t];                // == nE
    }
}

// B: scatter packed (src | dstLocal<<17) into bucket-contiguous buckEdges
__global__ __launch_bounds__(256)
void bucket_scatter(const int* __restrict__ src, const int* __restrict__ dst,
                    const int* __restrict__ partialCnt,
                    const int* __restrict__ bucketBase,
                    int* __restrict__ buckEdges, int nE, int chunk, int nbuck)
{
    __shared__ int bins[NBUCK_MAX];
    __shared__ int wOff[NBUCK_MAX];
    int blk = blockIdx.x, t = threadIdx.x;
    for (int i = t; i < nbuck; i += 256) {
        bins[i] = 0;
        wOff[i] = bucketBase[i] + partialCnt[(size_t)i * 256 + blk];
    }
    __syncthreads();
    int e0 = blk * chunk;
    int e1 = e0 + chunk; if (e1 > nE) e1 = nE;
    for (int e = e0 + t; e < e1; e += 256) {
        int d = dst[e];
        int sv = src[e];
        int bb = d >> BSHIFT;
        int r = atomicAdd(&bins[bb], 1);
        buckEdges[wOff[bb] + r] = sv | ((d & 127) << 17);
    }
}

// C: per-bucket: LDS count/scan 128 local bins -> rs (coalesced), assemble
// csr segment in LDS, flush coalesced. LDS atomics only.
__global__ __launch_bounds__(256)
void bucket_finalize(const int* __restrict__ buckEdges,
                     const int* __restrict__ bucketBase,
                     int* __restrict__ rs, int* __restrict__ csr,
                     int nN)
{
    __shared__ int eLds[SEGCAP];
    __shared__ int segLds[SEGCAP];
    __shared__ int deg[128];
    __shared__ int basec[128];
    __shared__ int cur[128];
    int b = blockIdx.x, t = threadIdx.x;
    int e0 = bucketBase[b], e1 = bucketBase[b + 1];
    int nb = e1 - e0;
    bool staged = (nb <= SEGCAP);
    if (t < 128) deg[t] = 0;
    __syncthreads();
    for (int i = t; i < nb; i += 256) {
        int p = buckEdges[e0 + i];
        if (staged) eLds[i] = p;
        atomicAdd(&deg[(p >> 17) & 127], 1);
    }
    __syncthreads();
    if (t < 128) basec[t] = deg[t];
    __syncthreads();
    for (int off = 1; off < 128; off <<= 1) {
        int u = 0;
        if (t < 128 && t >= off) u = basec[t - off];
        __syncthreads();
        if (t < 128) basec[t] += u;
        __syncthreads();
    }
    // basec inclusive; exclusive start = basec - deg
    int nodeBase = b << BSHIFT;
    if (t < 128) {
        int node = nodeBase + t;
        int ex = basec[t] - deg[t];
        if (node < nN) rs[node] = e0 + ex;
        cur[t] = ex;                 // running cursor (absolute-within-bucket)
    }
    __syncthreads();
    for (int i = t; i < nb; i += 256) {
        int p = staged ? eLds[i] : buckEdges[e0 + i];
        int dl = (p >> 17) & 127;
        int slot = atomicAdd(&cur[dl], 1);
        int sv = p & 0x1FFFF;
        if (staged) segLds[slot] = sv;
        else        csr[e0 + slot] = sv;
    }
    __syncthreads();
    if (staged)
        for (int i = t; i < nb; i += 256)
            csr[e0 + i] = segLds[i];
}

// ---------- fp32 -> bf16 conversion (8 elems/thread) ----------
__global__ __launch_bounds__(256)
void tobf16_kernel(const float* __restrict__ in, ushort_t* __restrict__ outh,
                   int nTot8)
{
    int i = blockIdx.x * 256 + threadIdx.x;
    if (i >= nTot8) return;
    float4 v0 = *(const float4*)(in + (size_t)i * 8);
    float4 v1 = *(const float4*)(in + (size_t)i * 8 + 4);
    uint4 o;
    o.x = (unsigned)f2bf(v0.x) | ((unsigned)f2bf(v0.y) << 16);
    o.y = (unsigned)f2bf(v0.z) | ((unsigned)f2bf(v0.w) << 16);
    o.z = (unsigned)f2bf(v1.x) | ((unsigned)f2bf(v1.y) << 16);
    o.w = (unsigned)f2bf(v1.z) | ((unsigned)f2bf(v1.w) << 16);
    *(uint4*)(outh + (size_t)i * 8) = o;
}

// ---------- weight precompute: collapse the two layers ----------
// MT1=(W2l*W1l)^T ; MT2=(W2l*W1r+W2r*W1l)^T ; MT3=(W2r*W1r)^T (transposed
// for contiguous scalar row loads). c1 = b1@W2l.T ; c0 = b1@W2r.T + b2
__global__ void prep_kernel(const float* __restrict__ W1l,
                            const float* __restrict__ W1r,
                            const float* __restrict__ W2l,
                            const float* __restrict__ W2r,
                            const float* __restrict__ b1,
                            const float* __restrict__ b2,
                            float* __restrict__ MT1, float* __restrict__ MT2,
                            float* __restrict__ MT3, float* __restrict__ c0,
                            float* __restrict__ c1)
{
    int f = blockIdx.x;      // 64 blocks
    int k = threadIdx.x;     // 64 threads
    float m1 = 0.f, m2 = 0.f, m3 = 0.f;
    for (int j = 0; j < DD; ++j) {
        float a2l = W2l[f * DD + j];
        float a2r = W2r[f * DD + j];
        float w1l = W1l[j * DD + k];
        float w1r = W1r[j * DD + k];
        m1 = fmaf(a2l, w1l, m1);
        m2 = fmaf(a2l, w1r, m2);
        m2 = fmaf(a2r, w1l, m2);
        m3 = fmaf(a2r, w1r, m3);
    }
    MT1[k * DD + f] = m1;
    MT2[k * DD + f] = m2;
    MT3[k * DD + f] = m3;
    float t1 = W2l[f * DD + k] * b1[k];
    float t0 = W2r[f * DD + k] * b1[k];
    for (int off = 1; off < 64; off <<= 1) {
        t1 += __shfl_xor(t1, off);
        t0 += __shfl_xor(t0, off);
    }
    if (k == 0) {
        c1[f] = t1;
        c0[f] = t0 + b2[f];
    }
}

// ---------- aggregation over bf16 rows: mean over neighbors ----------
__global__ __launch_bounds__(256, 4)
void aggregate_bf16(const ushort_t* __restrict__ xh,
                    const int* __restrict__ csr,
                    const int* __restrict__ rs,
                    ushort_t* __restrict__ aggrh, int nN)
{
    int lane = threadIdx.x & 63;
    int w = threadIdx.x >> 6;
    int g  = lane >> 3;        // group 0..7
    int gl = lane & 7;         // lane within group
    int totWaves = gridDim.x * 4;
    for (int node = blockIdx.x * 4 + w; node < nN; node += totWaves) {
        int beg = rs[node], end = rs[node + 1];
        int deg = end - beg;
        float4 l0 = {0,0,0,0}, h0 = {0,0,0,0};
        float4 l1 = {0,0,0,0}, h1 = {0,0,0,0};
        float4 l2 = {0,0,0,0}, h2 = {0,0,0,0};
        float4 l3 = {0,0,0,0}, h3 = {0,0,0,0};
        for (int base = beg; base < end; base += 64) {
            int n = end - base;
            if (n > 64) n = 64;
            int myIdx = csr[(lane < n) ? (base + lane) : base];
            for (int j = 0; j < n; j += 32) {
#define GSLOT(LO, HI, OFS)                                                    \
                {                                                             \
                    int ii = j + (OFS) + g;                                   \
                    int si = __shfl(myIdx, ii & 63);                          \
                    float mm = (ii < n) ? 1.f : 0.f;                          \
                    uint4 v = *(const uint4*)(xh + (size_t)si * DD + gl * 8); \
                    LO.x = fmaf(mm, bf_lo(v.x), LO.x);                        \
                    LO.y = fmaf(mm, bf_hi(v.x), LO.y);                        \
                    LO.z = fmaf(mm, bf_lo(v.y), LO.z);                        \
                    LO.w = fmaf(mm, bf_hi(v.y), LO.w);                        \
                    HI.x = fmaf(mm, bf_lo(v.z), HI.x);                        \
                    HI.y = fmaf(mm, bf_hi(v.z), HI.y);                        \
                    HI.z = fmaf(mm, bf_lo(v.w), HI.z);                        \
                    HI.w = fmaf(mm, bf_hi(v.w), HI.w);                        \
                }
                GSLOT(l0, h0, 0)  GSLOT(l1, h1, 8)
                GSLOT(l2, h2, 16) GSLOT(l3, h3, 24)
#undef GSLOT
            }
        }
        float4 lo, hi;
        lo.x = (l0.x + l1.x) + (l2.x + l3.x);
        lo.y = (l0.y + l1.y) + (l2.y + l3.y);
        lo.z = (l0.z + l1.z) + (l2.z + l3.z);
        lo.w = (l0.w + l1.w) + (l2.w + l3.w);
        hi.x = (h0.x + h1.x) + (h2.x + h3.x);
        hi.y = (h0.y + h1.y) + (h2.y + h3.y);
        hi.z = (h0.z + h1.z) + (h2.z + h3.z);
        hi.w = (h0.w + h1.w) + (h2.w + h3.w);
#pragma unroll
        for (int m = 8; m <= 32; m <<= 1) {
            lo.x += __shfl_xor(lo.x, m); lo.y += __shfl_xor(lo.y, m);
            lo.z += __shfl_xor(lo.z, m); lo.w += __shfl_xor(lo.w, m);
            hi.x += __shfl_xor(hi.x, m); hi.y += __shfl_xor(hi.y, m);
            hi.z += __shfl_xor(hi.z, m); hi.w += __shfl_xor(hi.w, m);
        }
        if (g == 0) {
            float inv = 1.0f / (float)(deg > 0 ? deg : 1);
            uint4 o;
            o.x = (unsigned)f2bf(lo.x * inv) | ((unsigned)f2bf(lo.y * inv) << 16);
            o.y = (unsigned)f2bf(lo.z * inv) | ((unsigned)f2bf(lo.w * inv) << 16);
            o.z = (unsigned)f2bf(hi.x * inv) | ((unsigned)f2bf(hi.y * inv) << 16);
            o.w = (unsigned)f2bf(hi.z * inv) | ((unsigned)f2bf(hi.w * inv) << 16);
            *(uint4*)(aggrh + (size_t)node * DD + gl * 8) = o;
        }
    }
}

// ---------- tri-dense: out = agg2@M1.T + agg1@M2.T + x@M3.T + bias ---------
__global__ __launch_bounds__(256)
void tri_dense5(const ushort_t* __restrict__ agg2h,
                const ushort_t* __restrict__ agg1h,
                const ushort_t* __restrict__ xh,
                const float* __restrict__ MT1,
                const float* __restrict__ MT2,
                const float* __restrict__ MT3,
                const float* __restrict__ c0,
                const float* __restrict__ c1,
                const int* __restrict__ rs,
                float* __restrict__ out, int nN)
{
    __shared__ float t_lds[DTILE * 65];
    int tid = threadIdx.x;
    int nl  = tid & 127;         // node within tile
    int fbase = __builtin_amdgcn_readfirstlane((tid >> 7) * 32);
    int base = blockIdx.x * DTILE;
    int node = base + nl;
    int gn = node < nN ? node : nN - 1;

    float ind = (rs[gn + 1] - rs[gn]) > 0 ? 1.0f : 0.0f;
    float acc[32];
#pragma unroll
    for (int j = 0; j < 32; ++j)
        acc[j] = fmaf(ind, c1[fbase + j], c0[fbase + j]);

#define STAGE(SRCH)                                                           \
    {                                                                         \
        _Pragma("unroll")                                                     \
        for (int i = 0; i < 4; ++i) {                                         \
            int fi = i * 256 + tid;        /* 0..1023 uint4 slots */          \
            int row = fi >> 3;                                                \
            int col = (fi & 7) * 8;                                           \
            int grow = base + row;                                            \
            if (grow >= nN) grow = nN - 1;                                    \
            uint4 v = *(const uint4*)((SRCH) + (size_t)grow * DD + col);      \
            float4 lo, hi;                                                    \
            lo.x = bf_lo(v.x); lo.y = bf_hi(v.x);                             \
            lo.z = bf_lo(v.y); lo.w = bf_hi(v.y);                             \
            hi.x = bf_lo(v.z); hi.y = bf_hi(v.z);                             \
            hi.z = bf_lo(v.w); hi.w = bf_hi(v.w);                             \
            *(float4*)&t_lds[row * 65 + col] = lo;                            \
            *(float4*)&t_lds[row * 65 + col + 4] = hi;                        \
        }                                                                     \
    }

#define PHASE(MT)                                                             \
    {                                                                         \
        _Pragma("unroll 1")                                                   \
        for (int k = 0; k < DD; ++k) {                                        \
            float ink = t_lds[nl * 65 + k];                                   \
            const float* mrow = (MT) + k * DD + fbase;                        \
            _Pragma("unroll")                                                 \
            for (int j = 0; j < 32; ++j)                                      \
                acc[j] = fmaf(ink, mrow[j], acc[j]);                          \
        }                                                                     \
    }

    STAGE(agg2h);
    __syncthreads();
    PHASE(MT1);
    __syncthreads();
    STAGE(agg1h);
    __syncthreads();
    PHASE(MT2);
    __syncthreads();
    STAGE(xh);
    __syncthreads();
    PHASE(MT3);
    __syncthreads();

    // funnel acc through LDS (reuse t_lds) for coalesced global stores
#pragma unroll
    for (int j = 0; j < 32; j += 4) {
        float4 o;
        o.x = acc[j]; o.y = acc[j + 1]; o.z = acc[j + 2]; o.w = acc[j + 3];
        *(float4*)&t_lds[nl * 65 + fbase + j] = o;
    }
    __syncthreads();
#pragma unroll
    for (int i = 0; i < 8; ++i) {
        int fi = i * 256 + tid;
        int row = fi >> 4;
        int col = (fi & 15) * 4;
        int grow = base + row;
        if (grow < nN)
            *(float4*)(out + (size_t)grow * DD + col) = *(float4*)&t_lds[row * 65 + col];
    }
#undef STAGE
#undef PHASE
}

extern "C" void kernel_launch(void* const* d_in, const int* in_sizes, int n_in,
                              void* d_out, int out_size, void* d_ws, size_t ws_size,
                              hipStream_t stream)
{
    const float* x   = (const float*)d_in[0];
    const int*   ei  = (const int*)d_in[1];
    const float* W1l = (const float*)d_in[2];
    const float* b1l = (const float*)d_in[3];
    const float* W1r = (const float*)d_in[4];
    const float* W2l = (const float*)d_in[5];
    const float* b2l = (const float*)d_in[6];
    const float* W2r = (const float*)d_in[7];
    float* out = (float*)d_out;

    int nN = in_sizes[0] / DD;   // 100000
    int nE = in_sizes[1] / 2;    // 1600000
    const int* src = ei;
    const int* dst = ei + nE;

    int nbuck = (nN + 127) >> BSHIFT;          // 782
    int chunk = (nE + 255) / 256;              // 6250

    // ws layout (float-sized slots):
    // rs[nN+1] | partialCnt[nbuck*256] | bucketTot[nbuck] | bucketBase[nbuck+1] |
    // csr[nE] | buckEdges[nE] | MT1,MT2,MT3[4096 ea] | c0,c1[64 ea] |
    // xh[nN*32] | agg1h[nN*32] | agg2h[nN*32]   (bf16, 12.8MB each)  ~52.5MB
    int* rs         = (int*)d_ws;
    int* partialCnt = rs + nN + 1;
    int* bucketTot  = partialCnt + (size_t)nbuck * 256;
    int* bucketBase = bucketTot + nbuck;
    int* csr        = bucketBase + nbuck + 1;
    int* buckEdges  = csr + nE;
    size_t ofs = (size_t)(buckEdges + nE - (int*)d_ws);
    ofs = (ofs + 3) & ~(size_t)3;
    float* MT1 = (float*)d_ws + ofs;
    float* MT2 = MT1 + DD * DD;
    float* MT3 = MT2 + DD * DD;
    float* c0 = MT3 + DD * DD;
    float* c1 = c0 + DD;
    float* xh_f    = c1 + DD;
    float* agg1h_f = xh_f + (size_t)nN * 32;
    float* agg2h_f = agg1h_f + (size_t)nN * 32;
    ushort_t* xh    = (ushort_t*)xh_f;
    ushort_t* agg1h = (ushort_t*)agg1h_f;
    ushort_t* agg2h = (ushort_t*)agg2h_f;

    int nden = (nN + DTILE - 1) / DTILE;       // 782
    int ncv  = (nN * 32 / 4 + 255) / 256;      // tobf16 blocks

    // CSR build — bucketed, zero global atomics, all-coalesced streams
    bucket_count<<<256, 256, 0, stream>>>(dst, partialCnt, nE, chunk, nbuck);
    bucket_scanblocks<<<nbuck, 256, 0, stream>>>(partialCnt, bucketTot);
    bucket_scanbase<<<1, 1024, 0, stream>>>(bucketTot, bucketBase, rs, nbuck, nN);
    bucket_scatter<<<256, 256, 0, stream>>>(src, dst, partialCnt, bucketBase,
                                            buckEdges, nE, chunk, nbuck);
    bucket_finalize<<<nbuck, 256, 0, stream>>>(buckEdges, bucketBase, rs, csr, nN);

    // weight collapse + x -> bf16
    prep_kernel<<<64, 64, 0, stream>>>(W1l, W1r, W2l, W2r, b1l, b2l,
                                       MT1, MT2, MT3, c0, c1);
    tobf16_kernel<<<ncv, 256, 0, stream>>>(x, xh, nN * DD / 8);

    // two bf16 aggregations
    aggregate_bf16<<<6144, 256, 0, stream>>>(xh, csr, rs, agg1h, nN);
    aggregate_bf16<<<6144, 256, 0, stream>>>(agg1h, csr, rs, agg2h, nN);

    // single fused dense pass (bf16 inputs, fp32 math/output)
    tri_dense5<<<nden, 256, 0, stream>>>(agg2h, agg1h, xh, MT1, MT2, MT3,
                                         c0, c1, rs, out, nN);
}

// Round 17
// 190.842 us; speedup vs baseline: 2.2299x; 1.0985x over previous
//
#include <hip/hip_runtime.h>

#define DD 64
#define DTILE 128
#define BSHIFT 7                 // 128 nodes per bucket
#define NBUCK_MAX 800
#define SEGCAP 4096

typedef unsigned short ushort_t;

static __device__ __forceinline__ unsigned short f2bf(float f)
{
    unsigned u = __float_as_uint(f);
    unsigned r = (u + 0x7FFFu + ((u >> 16) & 1u)) >> 16;   // round-nearest-even
    return (unsigned short)r;
}
static __device__ __forceinline__ float bf_lo(unsigned w) { return __uint_as_float(w << 16); }
static __device__ __forceinline__ float bf_hi(unsigned w) { return __uint_as_float(w & 0xFFFF0000u); }

// ================= bucketed CSR build (no global atomics) =================

// A: per-block LDS bucket histogram -> partialCnt[bucket*256+blk]
__global__ __launch_bounds__(256)
void bucket_count(const int* __restrict__ dst, int* __restrict__ partialCnt,
                  int nE, int chunk, int nbuck)
{
    __shared__ int bins[NBUCK_MAX];
    int blk = blockIdx.x, t = threadIdx.x;
    for (int i = t; i < nbuck; i += 256) bins[i] = 0;
    __syncthreads();
    int e0 = blk * chunk;
    int e1 = e0 + chunk; if (e1 > nE) e1 = nE;
    for (int e = e0 + t; e < e1; e += 256)
        atomicAdd(&bins[dst[e] >> BSHIFT], 1);
    __syncthreads();
    for (int i = t; i < nbuck; i += 256)
        partialCnt[(size_t)i * 256 + blk] = bins[i];
}

// A2: per-bucket exclusive scan over its 256 block counts; total -> bucketTot
__global__ __launch_bounds__(256)
void bucket_scanblocks(int* __restrict__ partialCnt, int* __restrict__ bucketTot)
{
    __shared__ int s[256];
    int b = blockIdx.x, t = threadIdx.x;
    int v = partialCnt[(size_t)b * 256 + t];
    s[t] = v;
    __syncthreads();
    for (int off = 1; off < 256; off <<= 1) {
        int u = (t >= off) ? s[t - off] : 0;
        __syncthreads();
        s[t] += u;
        __syncthreads();
    }
    partialCnt[(size_t)b * 256 + t] = s[t] - v;   // exclusive
    if (t == 255) bucketTot[b] = s[255];
}

// A3: exclusive scan over bucket totals -> bucketBase; also rs[nN]=nE
__global__ __launch_bounds__(1024)
void bucket_scanbase(const int* __restrict__ bucketTot, int* __restrict__ bucketBase,
                     int* __restrict__ rs, int nbuck, int nN)
{
    __shared__ int s[1024];
    int t = threadIdx.x;
    int v = (t < nbuck) ? bucketTot[t] : 0;
    s[t] = v;
    __syncthreads();
    for (int off = 1; off < 1024; off <<= 1) {
        int u = (t >= off) ? s[t - off] : 0;
        __syncthreads();
        s[t] += u;
        __syncthreads();
    }
    if (t < nbuck) bucketBase[t] = s[t] - v;
    if (t == nbuck - 1) {
        bucketBase[nbuck] = s[t];
        rs[nN] = s[t];                // == nE
    }
}

// B: scatter packed (src | dstLocal<<17) into bucket-contiguous buckEdges
__global__ __launch_bounds__(256)
void bucket_scatter(const int* __restrict__ src, const int* __restrict__ dst,
                    const int* __restrict__ partialCnt,
                    const int* __restrict__ bucketBase,
                    int* __restrict__ buckEdges, int nE, int chunk, int nbuck)
{
    __shared__ int bins[NBUCK_MAX];
    __shared__ int wOff[NBUCK_MAX];
    int blk = blockIdx.x, t = threadIdx.x;
    for (int i = t; i < nbuck; i += 256) {
        bins[i] = 0;
        wOff[i] = bucketBase[i] + partialCnt[(size_t)i * 256 + blk];
    }
    __syncthreads();
    int e0 = blk * chunk;
    int e1 = e0 + chunk; if (e1 > nE) e1 = nE;
    for (int e = e0 + t; e < e1; e += 256) {
        int d = dst[e];
        int sv = src[e];
        int bb = d >> BSHIFT;
        int r = atomicAdd(&bins[bb], 1);
        buckEdges[wOff[bb] + r] = sv | ((d & 127) << 17);
    }
}

// C: per-bucket finalize: rs + csr segment, all-LDS, coalesced flush
__global__ __launch_bounds__(256)
void bucket_finalize(const int* __restrict__ buckEdges,
                     const int* __restrict__ bucketBase,
                     int* __restrict__ rs, int* __restrict__ csr,
                     int nN)
{
    __shared__ int eLds[SEGCAP];
    __shared__ int segLds[SEGCAP];
    __shared__ int deg[128];
    __shared__ int basec[128];
    __shared__ int cur[128];
    int b = blockIdx.x, t = threadIdx.x;
    int e0 = bucketBase[b], e1 = bucketBase[b + 1];
    int nb = e1 - e0;
    bool staged = (nb <= SEGCAP);
    if (t < 128) deg[t] = 0;
    __syncthreads();
    for (int i = t; i < nb; i += 256) {
        int p = buckEdges[e0 + i];
        if (staged) eLds[i] = p;
        atomicAdd(&deg[(p >> 17) & 127], 1);
    }
    __syncthreads();
    if (t < 128) basec[t] = deg[t];
    __syncthreads();
    for (int off = 1; off < 128; off <<= 1) {
        int u = 0;
        if (t < 128 && t >= off) u = basec[t - off];
        __syncthreads();
        if (t < 128) basec[t] += u;
        __syncthreads();
    }
    int nodeBase = b << BSHIFT;
    if (t < 128) {
        int node = nodeBase + t;
        int ex = basec[t] - deg[t];
        if (node < nN) rs[node] = e0 + ex;
        cur[t] = ex;
    }
    __syncthreads();
    for (int i = t; i < nb; i += 256) {
        int p = staged ? eLds[i] : buckEdges[e0 + i];
        int dl = (p >> 17) & 127;
        int slot = atomicAdd(&cur[dl], 1);
        int sv = p & 0x1FFFF;
        if (staged) segLds[slot] = sv;
        else        csr[e0 + slot] = sv;
    }
    __syncthreads();
    if (staged)
        for (int i = t; i < nb; i += 256)
            csr[e0 + i] = segLds[i];
}

// ---------- fp32 -> bf16 conversion (8 elems/thread) ----------
__global__ __launch_bounds__(256)
void tobf16_kernel(const float* __restrict__ in, ushort_t* __restrict__ outh,
                   int nTot8)
{
    int i = blockIdx.x * 256 + threadIdx.x;
    if (i >= nTot8) return;
    float4 v0 = *(const float4*)(in + (size_t)i * 8);
    float4 v1 = *(const float4*)(in + (size_t)i * 8 + 4);
    uint4 o;
    o.x = (unsigned)f2bf(v0.x) | ((unsigned)f2bf(v0.y) << 16);
    o.y = (unsigned)f2bf(v0.z) | ((unsigned)f2bf(v0.w) << 16);
    o.z = (unsigned)f2bf(v1.x) | ((unsigned)f2bf(v1.y) << 16);
    o.w = (unsigned)f2bf(v1.z) | ((unsigned)f2bf(v1.w) << 16);
    *(uint4*)(outh + (size_t)i * 8) = o;
}

// ---------- weight precompute: collapse the two layers ----------
__global__ void prep_kernel(const float* __restrict__ W1l,
                            const float* __restrict__ W1r,
                            const float* __restrict__ W2l,
                            const float* __restrict__ W2r,
                            const float* __restrict__ b1,
                            const float* __restrict__ b2,
                            float* __restrict__ MT1, float* __restrict__ MT2,
                            float* __restrict__ MT3, float* __restrict__ c0,
                            float* __restrict__ c1)
{
    int f = blockIdx.x;      // 64 blocks
    int k = threadIdx.x;     // 64 threads
    float m1 = 0.f, m2 = 0.f, m3 = 0.f;
    for (int j = 0; j < DD; ++j) {
        float a2l = W2l[f * DD + j];
        float a2r = W2r[f * DD + j];
        float w1l = W1l[j * DD + k];
        float w1r = W1r[j * DD + k];
        m1 = fmaf(a2l, w1l, m1);
        m2 = fmaf(a2l, w1r, m2);
        m2 = fmaf(a2r, w1l, m2);
        m3 = fmaf(a2r, w1r, m3);
    }
    MT1[k * DD + f] = m1;
    MT2[k * DD + f] = m2;
    MT3[k * DD + f] = m3;
    float t1 = W2l[f * DD + k] * b1[k];
    float t0 = W2r[f * DD + k] * b1[k];
    for (int off = 1; off < 64; off <<= 1) {
        t1 += __shfl_xor(t1, off);
        t0 += __shfl_xor(t0, off);
    }
    if (k == 0) {
        c1[f] = t1;
        c0[f] = t0 + b2[f];
    }
}

// ---------- aggregation over bf16 rows: mean over neighbors ----------
__global__ __launch_bounds__(256, 4)
void aggregate_bf16(const ushort_t* __restrict__ xh,
                    const int* __restrict__ csr,
                    const int* __restrict__ rs,
                    ushort_t* __restrict__ aggrh, int nN)
{
    int lane = threadIdx.x & 63;
    int w = threadIdx.x >> 6;
    int g  = lane >> 3;        // group 0..7
    int gl = lane & 7;         // lane within group
    int totWaves = gridDim.x * 4;
    for (int node = blockIdx.x * 4 + w; node < nN; node += totWaves) {
        int beg = rs[node], end = rs[node + 1];
        int deg = end - beg;
        float4 l0 = {0,0,0,0}, h0 = {0,0,0,0};
        float4 l1 = {0,0,0,0}, h1 = {0,0,0,0};
        float4 l2 = {0,0,0,0}, h2 = {0,0,0,0};
        float4 l3 = {0,0,0,0}, h3 = {0,0,0,0};
        for (int base = beg; base < end; base += 64) {
            int n = end - base;
            if (n > 64) n = 64;
            int myIdx = csr[(lane < n) ? (base + lane) : base];
            for (int j = 0; j < n; j += 32) {
#define GSLOT(LO, HI, OFS)                                                    \
                {                                                             \
                    int ii = j + (OFS) + g;                                   \
                    int si = __shfl(myIdx, ii & 63);                          \
                    float mm = (ii < n) ? 1.f : 0.f;                          \
                    uint4 v = *(const uint4*)(xh + (size_t)si * DD + gl * 8); \
                    LO.x = fmaf(mm, bf_lo(v.x), LO.x);                        \
                    LO.y = fmaf(mm, bf_hi(v.x), LO.y);                        \
                    LO.z = fmaf(mm, bf_lo(v.y), LO.z);                        \
                    LO.w = fmaf(mm, bf_hi(v.y), LO.w);                        \
                    HI.x = fmaf(mm, bf_lo(v.z), HI.x);                        \
                    HI.y = fmaf(mm, bf_hi(v.z), HI.y);                        \
                    HI.z = fmaf(mm, bf_lo(v.w), HI.z);                        \
                    HI.w = fmaf(mm, bf_hi(v.w), HI.w);                        \
                }
                GSLOT(l0, h0, 0)  GSLOT(l1, h1, 8)
                GSLOT(l2, h2, 16) GSLOT(l3, h3, 24)
#undef GSLOT
            }
        }
        float4 lo, hi;
        lo.x = (l0.x + l1.x) + (l2.x + l3.x);
        lo.y = (l0.y + l1.y) + (l2.y + l3.y);
        lo.z = (l0.z + l1.z) + (l2.z + l3.z);
        lo.w = (l0.w + l1.w) + (l2.w + l3.w);
        hi.x = (h0.x + h1.x) + (h2.x + h3.x);
        hi.y = (h0.y + h1.y) + (h2.y + h3.y);
        hi.z = (h0.z + h1.z) + (h2.z + h3.z);
        hi.w = (h0.w + h1.w) + (h2.w + h3.w);
#pragma unroll
        for (int m = 8; m <= 32; m <<= 1) {
            lo.x += __shfl_xor(lo.x, m); lo.y += __shfl_xor(lo.y, m);
            lo.z += __shfl_xor(lo.z, m); lo.w += __shfl_xor(lo.w, m);
            hi.x += __shfl_xor(hi.x, m); hi.y += __shfl_xor(hi.y, m);
            hi.z += __shfl_xor(hi.z, m); hi.w += __shfl_xor(hi.w, m);
        }
        if (g == 0) {
            float inv = 1.0f / (float)(deg > 0 ? deg : 1);
            uint4 o;
            o.x = (unsigned)f2bf(lo.x * inv) | ((unsigned)f2bf(lo.y * inv) << 16);
            o.y = (unsigned)f2bf(lo.z * inv) | ((unsigned)f2bf(lo.w * inv) << 16);
            o.z = (unsigned)f2bf(hi.x * inv) | ((unsigned)f2bf(hi.y * inv) << 16);
            o.w = (unsigned)f2bf(hi.z * inv) | ((unsigned)f2bf(hi.w * inv) << 16);
            *(uint4*)(aggrh + (size_t)node * DD + gl * 8) = o;
        }
    }
}

// ---------- tri-dense v6: out = agg2@M1.T + agg1@M2.T + x@M3.T + bias ------
// 512 threads = (node, f-quarter): 2x waves of v5 (R16: occupancy 30%,
// VALU 26% — latency-exposed). k-unroll x4: 4 independent ds_read_b32
// issue together, then 4x16 fma -> 4x less lgkmcnt stall per fma.
// Weights still forced-scalar (readfirstlane fbase, 16 SGPR per j-loop).
__global__ __launch_bounds__(512)
void tri_dense6(const ushort_t* __restrict__ agg2h,
                const ushort_t* __restrict__ agg1h,
                const ushort_t* __restrict__ xh,
                const float* __restrict__ MT1,
                const float* __restrict__ MT2,
                const float* __restrict__ MT3,
                const float* __restrict__ c0,
                const float* __restrict__ c1,
                const int* __restrict__ rs,
                float* __restrict__ out, int nN)
{
    __shared__ float t_lds[DTILE * 65];
    int tid = threadIdx.x;          // 0..511
    int nl  = tid & 127;            // node within tile
    int fbase = __builtin_amdgcn_readfirstlane((tid >> 7) * 16); // 0/16/32/48
    int base = blockIdx.x * DTILE;
    int node = base + nl;
    int gn = node < nN ? node : nN - 1;

    float ind = (rs[gn + 1] - rs[gn]) > 0 ? 1.0f : 0.0f;
    float acc[16];
#pragma unroll
    for (int j = 0; j < 16; ++j)
        acc[j] = fmaf(ind, c1[fbase + j], c0[fbase + j]);

#define STAGE(SRCH)                                                           \
    {                                                                         \
        _Pragma("unroll")                                                     \
        for (int i = 0; i < 2; ++i) {                                         \
            int fi = i * 512 + tid;        /* 0..1023 uint4 slots */          \
            int row = fi >> 3;                                                \
            int col = (fi & 7) * 8;                                           \
            int grow = base + row;                                            \
            if (grow >= nN) grow = nN - 1;                                    \
            uint4 v = *(const uint4*)((SRCH) + (size_t)grow * DD + col);      \
            float4 lo, hi;                                                    \
            lo.x = bf_lo(v.x); lo.y = bf_hi(v.x);                             \
            lo.z = bf_lo(v.y); lo.w = bf_hi(v.y);                             \
            hi.x = bf_lo(v.z); hi.y = bf_hi(v.z);                             \
            hi.z = bf_lo(v.w); hi.w = bf_hi(v.w);                             \
            *(float4*)&t_lds[row * 65 + col] = lo;                            \
            *(float4*)&t_lds[row * 65 + col + 4] = hi;                        \
        }                                                                     \
    }

#define PHASE(MT)                                                             \
    {                                                                         \
        _Pragma("unroll 1")                                                   \
        for (int k = 0; k < DD; k += 4) {                                     \
            float i0 = t_lds[nl * 65 + k + 0];                                \
            float i1 = t_lds[nl * 65 + k + 1];                                \
            float i2 = t_lds[nl * 65 + k + 2];                                \
            float i3 = t_lds[nl * 65 + k + 3];                                \
            const float* mr = (MT) + k * DD + fbase;                          \
            _Pragma("unroll")                                                 \
            for (int j = 0; j < 16; ++j) acc[j] = fmaf(i0, mr[j], acc[j]);    \
            _Pragma("unroll")                                                 \
            for (int j = 0; j < 16; ++j) acc[j] = fmaf(i1, mr[DD + j], acc[j]); \
            _Pragma("unroll")                                                 \
            for (int j = 0; j < 16; ++j) acc[j] = fmaf(i2, mr[2 * DD + j], acc[j]); \
            _Pragma("unroll")                                                 \
            for (int j = 0; j < 16; ++j) acc[j] = fmaf(i3, mr[3 * DD + j], acc[j]); \
        }                                                                     \
    }

    STAGE(agg2h);
    __syncthreads();
    PHASE(MT1);
    __syncthreads();
    STAGE(agg1h);
    __syncthreads();
    PHASE(MT2);
    __syncthreads();
    STAGE(xh);
    __syncthreads();
    PHASE(MT3);
    __syncthreads();

    // funnel acc through LDS (reuse t_lds) for coalesced global stores
#pragma unroll
    for (int j = 0; j < 16; j += 4) {
        float4 o;
        o.x = acc[j]; o.y = acc[j + 1]; o.z = acc[j + 2]; o.w = acc[j + 3];
        *(float4*)&t_lds[nl * 65 + fbase + j] = o;
    }
    __syncthreads();
#pragma unroll
    for (int i = 0; i < 4; ++i) {
        int fi = i * 512 + tid;        // 0..2047 float4 slots
        int row = fi >> 4;
        int col = (fi & 15) * 4;
        int grow = base + row;
        if (grow < nN)
            *(float4*)(out + (size_t)grow * DD + col) = *(float4*)&t_lds[row * 65 + col];
    }
#undef STAGE
#undef PHASE
}

extern "C" void kernel_launch(void* const* d_in, const int* in_sizes, int n_in,
                              void* d_out, int out_size, void* d_ws, size_t ws_size,
                              hipStream_t stream)
{
    const float* x   = (const float*)d_in[0];
    const int*   ei  = (const int*)d_in[1];
    const float* W1l = (const float*)d_in[2];
    const float* b1l = (const float*)d_in[3];
    const float* W1r = (const float*)d_in[4];
    const float* W2l = (const float*)d_in[5];
    const float* b2l = (const float*)d_in[6];
    const float* W2r = (const float*)d_in[7];
    float* out = (float*)d_out;

    int nN = in_sizes[0] / DD;   // 100000
    int nE = in_sizes[1] / 2;    // 1600000
    const int* src = ei;
    const int* dst = ei + nE;

    int nbuck = (nN + 127) >> BSHIFT;          // 782
    int chunk = (nE + 255) / 256;              // 6250

    // ws layout (float-sized slots):
    // rs[nN+1] | partialCnt[nbuck*256] | bucketTot[nbuck] | bucketBase[nbuck+1] |
    // csr[nE] | buckEdges[nE] | MT1,MT2,MT3[4096 ea] | c0,c1[64 ea] |
    // xh[nN*32] | agg1h[nN*32] | agg2h[nN*32]   (bf16, 12.8MB each)
    int* rs         = (int*)d_ws;
    int* partialCnt = rs + nN + 1;
    int* bucketTot  = partialCnt + (size_t)nbuck * 256;
    int* bucketBase = bucketTot + nbuck;
    int* csr        = bucketBase + nbuck + 1;
    int* buckEdges  = csr + nE;
    size_t ofs = (size_t)(buckEdges + nE - (int*)d_ws);
    ofs = (ofs + 3) & ~(size_t)3;
    float* MT1 = (float*)d_ws + ofs;
    float* MT2 = MT1 + DD * DD;
    float* MT3 = MT2 + DD * DD;
    float* c0 = MT3 + DD * DD;
    float* c1 = c0 + DD;
    float* xh_f    = c1 + DD;
    float* agg1h_f = xh_f + (size_t)nN * 32;
    float* agg2h_f = agg1h_f + (size_t)nN * 32;
    ushort_t* xh    = (ushort_t*)xh_f;
    ushort_t* agg1h = (ushort_t*)agg1h_f;
    ushort_t* agg2h = (ushort_t*)agg2h_f;

    int nden = (nN + DTILE - 1) / DTILE;       // 782
    int ncv  = (nN * 32 / 4 + 255) / 256;      // tobf16 blocks

    // CSR build — bucketed, zero global atomics, all-coalesced streams
    bucket_count<<<256, 256, 0, stream>>>(dst, partialCnt, nE, chunk, nbuck);
    bucket_scanblocks<<<nbuck, 256, 0, stream>>>(partialCnt, bucketTot);
    bucket_scanbase<<<1, 1024, 0, stream>>>(bucketTot, bucketBase, rs, nbuck, nN);
    bucket_scatter<<<256, 256, 0, stream>>>(src, dst, partialCnt, bucketBase,
                                            buckEdges, nE, chunk, nbuck);
    bucket_finalize<<<nbuck, 256, 0, stream>>>(buckEdges, bucketBase, rs, csr, nN);

    // weight collapse + x -> bf16
    prep_kernel<<<64, 64, 0, stream>>>(W1l, W1r, W2l, W2r, b1l, b2l,
                                       MT1, MT2, MT3, c0, c1);
    tobf16_kernel<<<ncv, 256, 0, stream>>>(x, xh, nN * DD / 8);

    // two bf16 aggregations
    aggregate_bf16<<<6144, 256, 0, stream>>>(xh, csr, rs, agg1h, nN);
    aggregate_bf16<<<6144, 256, 0, stream>>>(agg1h, csr, rs, agg2h, nN);

    // single fused dense pass (512 thr, 4 f-quarters, k-unroll-4)
    tri_dense6<<<nden, 512, 0, stream>>>(agg2h, agg1h, xh, MT1, MT2, MT3,
                                         c0, c1, rs, out, nN);
}

// Round 18
// 159.307 us; speedup vs baseline: 2.6713x; 1.1980x over previous
//
#include <hip/hip_runtime.h>

#define DD 64
#define DTILE 128
#define BSHIFT 7                 // 128 nodes per bucket
#define NBUCK_MAX 800
#define SEGCAP 4096

typedef unsigned short ushort_t;

static __device__ __forceinline__ unsigned short f2bf(float f)
{
    unsigned u = __float_as_uint(f);
    unsigned r = (u + 0x7FFFu + ((u >> 16) & 1u)) >> 16;   // round-nearest-even
    return (unsigned short)r;
}
static __device__ __forceinline__ float bf_lo(unsigned w) { return __uint_as_float(w << 16); }
static __device__ __forceinline__ float bf_hi(unsigned w) { return __uint_as_float(w & 0xFFFF0000u); }

// ================= bucketed CSR build (no global atomics) =================

// A: per-block LDS bucket histogram -> partialCnt[bucket*256+blk]
__global__ __launch_bounds__(256)
void bucket_count(const int* __restrict__ dst, int* __restrict__ partialCnt,
                  int nE, int chunk, int nbuck)
{
    __shared__ int bins[NBUCK_MAX];
    int blk = blockIdx.x, t = threadIdx.x;
    for (int i = t; i < nbuck; i += 256) bins[i] = 0;
    __syncthreads();
    int e0 = blk * chunk;
    int e1 = e0 + chunk; if (e1 > nE) e1 = nE;
    for (int e = e0 + t; e < e1; e += 256)
        atomicAdd(&bins[dst[e] >> BSHIFT], 1);
    __syncthreads();
    for (int i = t; i < nbuck; i += 256)
        partialCnt[(size_t)i * 256 + blk] = bins[i];
}

// A2: per-bucket exclusive scan over its 256 block counts; total -> bucketTot
__global__ __launch_bounds__(256)
void bucket_scanblocks(int* __restrict__ partialCnt, int* __restrict__ bucketTot)
{
    __shared__ int s[256];
    int b = blockIdx.x, t = threadIdx.x;
    int v = partialCnt[(size_t)b * 256 + t];
    s[t] = v;
    __syncthreads();
    for (int off = 1; off < 256; off <<= 1) {
        int u = (t >= off) ? s[t - off] : 0;
        __syncthreads();
        s[t] += u;
        __syncthreads();
    }
    partialCnt[(size_t)b * 256 + t] = s[t] - v;   // exclusive
    if (t == 255) bucketTot[b] = s[255];
}

// A3: exclusive scan over bucket totals -> bucketBase; also rs[nN]=nE
__global__ __launch_bounds__(1024)
void bucket_scanbase(const int* __restrict__ bucketTot, int* __restrict__ bucketBase,
                     int* __restrict__ rs, int nbuck, int nN)
{
    __shared__ int s[1024];
    int t = threadIdx.x;
    int v = (t < nbuck) ? bucketTot[t] : 0;
    s[t] = v;
    __syncthreads();
    for (int off = 1; off < 1024; off <<= 1) {
        int u = (t >= off) ? s[t - off] : 0;
        __syncthreads();
        s[t] += u;
        __syncthreads();
    }
    if (t < nbuck) bucketBase[t] = s[t] - v;
    if (t == nbuck - 1) {
        bucketBase[nbuck] = s[t];
        rs[nN] = s[t];                // == nE
    }
}

// B: scatter packed (src | dstLocal<<17) into bucket-contiguous buckEdges
__global__ __launch_bounds__(256)
void bucket_scatter(const int* __restrict__ src, const int* __restrict__ dst,
                    const int* __restrict__ partialCnt,
                    const int* __restrict__ bucketBase,
                    int* __restrict__ buckEdges, int nE, int chunk, int nbuck)
{
    __shared__ int bins[NBUCK_MAX];
    __shared__ int wOff[NBUCK_MAX];
    int blk = blockIdx.x, t = threadIdx.x;
    for (int i = t; i < nbuck; i += 256) {
        bins[i] = 0;
        wOff[i] = bucketBase[i] + partialCnt[(size_t)i * 256 + blk];
    }
    __syncthreads();
    int e0 = blk * chunk;
    int e1 = e0 + chunk; if (e1 > nE) e1 = nE;
    for (int e = e0 + t; e < e1; e += 256) {
        int d = dst[e];
        int sv = src[e];
        int bb = d >> BSHIFT;
        int r = atomicAdd(&bins[bb], 1);
        buckEdges[wOff[bb] + r] = sv | ((d & 127) << 17);
    }
}

// C: per-bucket finalize: rs + csr segment, all-LDS, coalesced flush
__global__ __launch_bounds__(256)
void bucket_finalize(const int* __restrict__ buckEdges,
                     const int* __restrict__ bucketBase,
                     int* __restrict__ rs, int* __restrict__ csr,
                     int nN)
{
    __shared__ int eLds[SEGCAP];
    __shared__ int segLds[SEGCAP];
    __shared__ int deg[128];
    __shared__ int basec[128];
    __shared__ int cur[128];
    int b = blockIdx.x, t = threadIdx.x;
    int e0 = bucketBase[b], e1 = bucketBase[b + 1];
    int nb = e1 - e0;
    bool staged = (nb <= SEGCAP);
    if (t < 128) deg[t] = 0;
    __syncthreads();
    for (int i = t; i < nb; i += 256) {
        int p = buckEdges[e0 + i];
        if (staged) eLds[i] = p;
        atomicAdd(&deg[(p >> 17) & 127], 1);
    }
    __syncthreads();
    if (t < 128) basec[t] = deg[t];
    __syncthreads();
    for (int off = 1; off < 128; off <<= 1) {
        int u = 0;
        if (t < 128 && t >= off) u = basec[t - off];
        __syncthreads();
        if (t < 128) basec[t] += u;
        __syncthreads();
    }
    int nodeBase = b << BSHIFT;
    if (t < 128) {
        int node = nodeBase + t;
        int ex = basec[t] - deg[t];
        if (node < nN) rs[node] = e0 + ex;
        cur[t] = ex;
    }
    __syncthreads();
    for (int i = t; i < nb; i += 256) {
        int p = staged ? eLds[i] : buckEdges[e0 + i];
        int dl = (p >> 17) & 127;
        int slot = atomicAdd(&cur[dl], 1);
        int sv = p & 0x1FFFF;
        if (staged) segLds[slot] = sv;
        else        csr[e0 + slot] = sv;
    }
    __syncthreads();
    if (staged)
        for (int i = t; i < nb; i += 256)
            csr[e0 + i] = segLds[i];
}

// ---------- fp32 -> bf16 conversion (8 elems/thread) ----------
__global__ __launch_bounds__(256)
void tobf16_kernel(const float* __restrict__ in, ushort_t* __restrict__ outh,
                   int nTot8)
{
    int i = blockIdx.x * 256 + threadIdx.x;
    if (i >= nTot8) return;
    float4 v0 = *(const float4*)(in + (size_t)i * 8);
    float4 v1 = *(const float4*)(in + (size_t)i * 8 + 4);
    uint4 o;
    o.x = (unsigned)f2bf(v0.x) | ((unsigned)f2bf(v0.y) << 16);
    o.y = (unsigned)f2bf(v0.z) | ((unsigned)f2bf(v0.w) << 16);
    o.z = (unsigned)f2bf(v1.x) | ((unsigned)f2bf(v1.y) << 16);
    o.w = (unsigned)f2bf(v1.z) | ((unsigned)f2bf(v1.w) << 16);
    *(uint4*)(outh + (size_t)i * 8) = o;
}

// ---------- weight precompute: collapse the two layers ----------
__global__ void prep_kernel(const float* __restrict__ W1l,
                            const float* __restrict__ W1r,
                            const float* __restrict__ W2l,
                            const float* __restrict__ W2r,
                            const float* __restrict__ b1,
                            const float* __restrict__ b2,
                            float* __restrict__ MT1, float* __restrict__ MT2,
                            float* __restrict__ MT3, float* __restrict__ c0,
                            float* __restrict__ c1)
{
    int f = blockIdx.x;      // 64 blocks
    int k = threadIdx.x;     // 64 threads
    float m1 = 0.f, m2 = 0.f, m3 = 0.f;
    for (int j = 0; j < DD; ++j) {
        float a2l = W2l[f * DD + j];
        float a2r = W2r[f * DD + j];
        float w1l = W1l[j * DD + k];
        float w1r = W1r[j * DD + k];
        m1 = fmaf(a2l, w1l, m1);
        m2 = fmaf(a2l, w1r, m2);
        m2 = fmaf(a2r, w1l, m2);
        m3 = fmaf(a2r, w1r, m3);
    }
    MT1[k * DD + f] = m1;
    MT2[k * DD + f] = m2;
    MT3[k * DD + f] = m3;
    float t1 = W2l[f * DD + k] * b1[k];
    float t0 = W2r[f * DD + k] * b1[k];
    for (int off = 1; off < 64; off <<= 1) {
        t1 += __shfl_xor(t1, off);
        t0 += __shfl_xor(t0, off);
    }
    if (k == 0) {
        c1[f] = t1;
        c0[f] = t0 + b2[f];
    }
}

// ---------- aggregation, group-per-node: mean over neighbors ----------
// 8-lane group owns ONE node (8 nodes/wave); lane gl owns features
// [gl*8, gl*8+8) and accumulates over rows -> NO cross-lane reduce, masked
// waste only in the <8-row tail, and the wave's 8 consecutive nodes give a
// contiguous 1KB store. 4 accumulator sets keep 4 gathers in flight/lane.
__global__ __launch_bounds__(256, 4)
void aggregate_bf16g(const ushort_t* __restrict__ xh,
                     const int* __restrict__ csr,
                     const int* __restrict__ rs,
                     ushort_t* __restrict__ aggrh, int nN)
{
    int lane = threadIdx.x & 63;
    int w = threadIdx.x >> 6;
    int g  = lane >> 3;        // group 0..7: node owner
    int gl = lane & 7;         // lane within group
    int node = (blockIdx.x * 4 + w) * 8 + g;
    int valid = node < nN;
    int nd = valid ? node : nN - 1;
    int beg = rs[nd], end = rs[nd + 1];
    int deg = end - beg;

    float4 aL0 = {0,0,0,0}, aH0 = {0,0,0,0};
    float4 aL1 = {0,0,0,0}, aH1 = {0,0,0,0};
    float4 aL2 = {0,0,0,0}, aH2 = {0,0,0,0};
    float4 aL3 = {0,0,0,0}, aH3 = {0,0,0,0};

#define ROWA(S, L, H)                                                         \
    {                                                                         \
        uint4 v = *(const uint4*)(xh + (size_t)(S) * DD + gl * 8);            \
        L.x += bf_lo(v.x); L.y += bf_hi(v.x);                                 \
        L.z += bf_lo(v.y); L.w += bf_hi(v.y);                                 \
        H.x += bf_lo(v.z); H.y += bf_hi(v.z);                                 \
        H.z += bf_lo(v.w); H.w += bf_hi(v.w);                                 \
    }
#define ROWM(S, MM, L, H)                                                     \
    {                                                                         \
        uint4 v = *(const uint4*)(xh + (size_t)(S) * DD + gl * 8);            \
        L.x = fmaf(MM, bf_lo(v.x), L.x); L.y = fmaf(MM, bf_hi(v.x), L.y);     \
        L.z = fmaf(MM, bf_lo(v.y), L.z); L.w = fmaf(MM, bf_hi(v.y), L.w);     \
        H.x = fmaf(MM, bf_lo(v.z), H.x); H.y = fmaf(MM, bf_hi(v.z), H.y);     \
        H.z = fmaf(MM, bf_lo(v.w), H.z); H.w = fmaf(MM, bf_hi(v.w), H.w);     \
    }

    for (int ch = 0; ch < deg; ch += 8) {
        int ii = ch + gl;
        int myIdx = csr[(ii < deg) ? (beg + ii) : beg];
        int lb = g << 3;
        if (ch + 8 <= deg) {           // full chunk: no masks
            int s0 = __shfl(myIdx, lb + 0);
            int s1 = __shfl(myIdx, lb + 1);
            int s2 = __shfl(myIdx, lb + 2);
            int s3 = __shfl(myIdx, lb + 3);
            ROWA(s0, aL0, aH0) ROWA(s1, aL1, aH1)
            ROWA(s2, aL2, aH2) ROWA(s3, aL3, aH3)
            int s4 = __shfl(myIdx, lb + 4);
            int s5 = __shfl(myIdx, lb + 5);
            int s6 = __shfl(myIdx, lb + 6);
            int s7 = __shfl(myIdx, lb + 7);
            ROWA(s4, aL0, aH0) ROWA(s5, aL1, aH1)
            ROWA(s6, aL2, aH2) ROWA(s7, aL3, aH3)
        } else {                       // tail chunk: masked
            int rem = deg - ch;
            int s0 = __shfl(myIdx, lb + 0);
            int s1 = __shfl(myIdx, lb + 1);
            int s2 = __shfl(myIdx, lb + 2);
            int s3 = __shfl(myIdx, lb + 3);
            float m0 = (0 < rem) ? 1.f : 0.f;
            float m1 = (1 < rem) ? 1.f : 0.f;
            float m2 = (2 < rem) ? 1.f : 0.f;
            float m3 = (3 < rem) ? 1.f : 0.f;
            ROWM(s0, m0, aL0, aH0) ROWM(s1, m1, aL1, aH1)
            ROWM(s2, m2, aL2, aH2) ROWM(s3, m3, aL3, aH3)
            int s4 = __shfl(myIdx, lb + 4);
            int s5 = __shfl(myIdx, lb + 5);
            int s6 = __shfl(myIdx, lb + 6);
            int s7 = __shfl(myIdx, lb + 7);
            float m4 = (4 < rem) ? 1.f : 0.f;
            float m5 = (5 < rem) ? 1.f : 0.f;
            float m6 = (6 < rem) ? 1.f : 0.f;
            float m7 = (7 < rem) ? 1.f : 0.f;
            ROWM(s4, m4, aL0, aH0) ROWM(s5, m5, aL1, aH1)
            ROWM(s6, m6, aL2, aH2) ROWM(s7, m7, aL3, aH3)
        }
    }
#undef ROWA
#undef ROWM

    float4 L, H;
    L.x = (aL0.x + aL1.x) + (aL2.x + aL3.x);
    L.y = (aL0.y + aL1.y) + (aL2.y + aL3.y);
    L.z = (aL0.z + aL1.z) + (aL2.z + aL3.z);
    L.w = (aL0.w + aL1.w) + (aL2.w + aL3.w);
    H.x = (aH0.x + aH1.x) + (aH2.x + aH3.x);
    H.y = (aH0.y + aH1.y) + (aH2.y + aH3.y);
    H.z = (aH0.z + aH1.z) + (aH2.z + aH3.z);
    H.w = (aH0.w + aH1.w) + (aH2.w + aH3.w);
    if (valid) {
        float inv = 1.0f / (float)(deg > 0 ? deg : 1);
        uint4 o;
        o.x = (unsigned)f2bf(L.x * inv) | ((unsigned)f2bf(L.y * inv) << 16);
        o.y = (unsigned)f2bf(L.z * inv) | ((unsigned)f2bf(L.w * inv) << 16);
        o.z = (unsigned)f2bf(H.x * inv) | ((unsigned)f2bf(H.y * inv) << 16);
        o.w = (unsigned)f2bf(H.z * inv) | ((unsigned)f2bf(H.w * inv) << 16);
        *(uint4*)(aggrh + (size_t)node * DD + gl * 8) = o;
    }
}

// ---------- tri-dense v6: out = agg2@M1.T + agg1@M2.T + x@M3.T + bias ------
__global__ __launch_bounds__(512)
void tri_dense6(const ushort_t* __restrict__ agg2h,
                const ushort_t* __restrict__ agg1h,
                const ushort_t* __restrict__ xh,
                const float* __restrict__ MT1,
                const float* __restrict__ MT2,
                const float* __restrict__ MT3,
                const float* __restrict__ c0,
                const float* __restrict__ c1,
                const int* __restrict__ rs,
                float* __restrict__ out, int nN)
{
    __shared__ float t_lds[DTILE * 65];
    int tid = threadIdx.x;          // 0..511
    int nl  = tid & 127;            // node within tile
    int fbase = __builtin_amdgcn_readfirstlane((tid >> 7) * 16); // 0/16/32/48
    int base = blockIdx.x * DTILE;
    int node = base + nl;
    int gn = node < nN ? node : nN - 1;

    float ind = (rs[gn + 1] - rs[gn]) > 0 ? 1.0f : 0.0f;
    float acc[16];
#pragma unroll
    for (int j = 0; j < 16; ++j)
        acc[j] = fmaf(ind, c1[fbase + j], c0[fbase + j]);

#define STAGE(SRCH)                                                           \
    {                                                                         \
        _Pragma("unroll")                                                     \
        for (int i = 0; i < 2; ++i) {                                         \
            int fi = i * 512 + tid;        /* 0..1023 uint4 slots */          \
            int row = fi >> 3;                                                \
            int col = (fi & 7) * 8;                                           \
            int grow = base + row;                                            \
            if (grow >= nN) grow = nN - 1;                                    \
            uint4 v = *(const uint4*)((SRCH) + (size_t)grow * DD + col);      \
            float4 lo, hi;                                                    \
            lo.x = bf_lo(v.x); lo.y = bf_hi(v.x);                             \
            lo.z = bf_lo(v.y); lo.w = bf_hi(v.y);                             \
            hi.x = bf_lo(v.z); hi.y = bf_hi(v.z);                             \
            hi.z = bf_lo(v.w); hi.w = bf_hi(v.w);                             \
            *(float4*)&t_lds[row * 65 + col] = lo;                            \
            *(float4*)&t_lds[row * 65 + col + 4] = hi;                        \
        }                                                                     \
    }

#define PHASE(MT)                                                             \
    {                                                                         \
        _Pragma("unroll 1")                                                   \
        for (int k = 0; k < DD; k += 4) {                                     \
            float i0 = t_lds[nl * 65 + k + 0];                                \
            float i1 = t_lds[nl * 65 + k + 1];                                \
            float i2 = t_lds[nl * 65 + k + 2];                                \
            float i3 = t_lds[nl * 65 + k + 3];                                \
            const float* mr = (MT) + k * DD + fbase;                          \
            _Pragma("unroll")                                                 \
            for (int j = 0; j < 16; ++j) acc[j] = fmaf(i0, mr[j], acc[j]);    \
            _Pragma("unroll")                                                 \
            for (int j = 0; j < 16; ++j) acc[j] = fmaf(i1, mr[DD + j], acc[j]); \
            _Pragma("unroll")                                                 \
            for (int j = 0; j < 16; ++j) acc[j] = fmaf(i2, mr[2 * DD + j], acc[j]); \
            _Pragma("unroll")                                                 \
            for (int j = 0; j < 16; ++j) acc[j] = fmaf(i3, mr[3 * DD + j], acc[j]); \
        }                                                                     \
    }

    STAGE(agg2h);
    __syncthreads();
    PHASE(MT1);
    __syncthreads();
    STAGE(agg1h);
    __syncthreads();
    PHASE(MT2);
    __syncthreads();
    STAGE(xh);
    __syncthreads();
    PHASE(MT3);
    __syncthreads();

    // funnel acc through LDS (reuse t_lds) for coalesced global stores
#pragma unroll
    for (int j = 0; j < 16; j += 4) {
        float4 o;
        o.x = acc[j]; o.y = acc[j + 1]; o.z = acc[j + 2]; o.w = acc[j + 3];
        *(float4*)&t_lds[nl * 65 + fbase + j] = o;
    }
    __syncthreads();
#pragma unroll
    for (int i = 0; i < 4; ++i) {
        int fi = i * 512 + tid;        // 0..2047 float4 slots
        int row = fi >> 4;
        int col = (fi & 15) * 4;
        int grow = base + row;
        if (grow < nN)
            *(float4*)(out + (size_t)grow * DD + col) = *(float4*)&t_lds[row * 65 + col];
    }
#undef STAGE
#undef PHASE
}

extern "C" void kernel_launch(void* const* d_in, const int* in_sizes, int n_in,
                              void* d_out, int out_size, void* d_ws, size_t ws_size,
                              hipStream_t stream)
{
    const float* x   = (const float*)d_in[0];
    const int*   ei  = (const int*)d_in[1];
    const float* W1l = (const float*)d_in[2];
    const float* b1l = (const float*)d_in[3];
    const float* W1r = (const float*)d_in[4];
    const float* W2l = (const float*)d_in[5];
    const float* b2l = (const float*)d_in[6];
    const float* W2r = (const float*)d_in[7];
    float* out = (float*)d_out;

    int nN = in_sizes[0] / DD;   // 100000
    int nE = in_sizes[1] / 2;    // 1600000
    const int* src = ei;
    const int* dst = ei + nE;

    int nbuck = (nN + 127) >> BSHIFT;          // 782
    int chunk = (nE + 255) / 256;              // 6250

    // ws layout (float-sized slots):
    // rs[nN+1] | partialCnt[nbuck*256] | bucketTot[nbuck] | bucketBase[nbuck+1] |
    // csr[nE] | buckEdges[nE] | MT1,MT2,MT3[4096 ea] | c0,c1[64 ea] |
    // xh[nN*32] | agg1h[nN*32] | agg2h[nN*32]   (bf16, 12.8MB each)
    int* rs         = (int*)d_ws;
    int* partialCnt = rs + nN + 1;
    int* bucketTot  = partialCnt + (size_t)nbuck * 256;
    int* bucketBase = bucketTot + nbuck;
    int* csr        = bucketBase + nbuck + 1;
    int* buckEdges  = csr + nE;
    size_t ofs = (size_t)(buckEdges + nE - (int*)d_ws);
    ofs = (ofs + 3) & ~(size_t)3;
    float* MT1 = (float*)d_ws + ofs;
    float* MT2 = MT1 + DD * DD;
    float* MT3 = MT2 + DD * DD;
    float* c0 = MT3 + DD * DD;
    float* c1 = c0 + DD;
    float* xh_f    = c1 + DD;
    float* agg1h_f = xh_f + (size_t)nN * 32;
    float* agg2h_f = agg1h_f + (size_t)nN * 32;
    ushort_t* xh    = (ushort_t*)xh_f;
    ushort_t* agg1h = (ushort_t*)agg1h_f;
    ushort_t* agg2h = (ushort_t*)agg2h_f;

    int nden = (nN + DTILE - 1) / DTILE;       // 782
    int ncv  = (nN * 32 / 4 + 255) / 256;      // tobf16 blocks
    int nagg = (nN + 31) / 32;                 // 3125 blocks (32 nodes/block)

    // CSR build — bucketed, zero global atomics, all-coalesced streams
    bucket_count<<<256, 256, 0, stream>>>(dst, partialCnt, nE, chunk, nbuck);
    bucket_scanblocks<<<nbuck, 256, 0, stream>>>(partialCnt, bucketTot);
    bucket_scanbase<<<1, 1024, 0, stream>>>(bucketTot, bucketBase, rs, nbuck, nN);
    bucket_scatter<<<256, 256, 0, stream>>>(src, dst, partialCnt, bucketBase,
                                            buckEdges, nE, chunk, nbuck);
    bucket_finalize<<<nbuck, 256, 0, stream>>>(buckEdges, bucketBase, rs, csr, nN);

    // weight collapse + x -> bf16
    prep_kernel<<<64, 64, 0, stream>>>(W1l, W1r, W2l, W2r, b1l, b2l,
                                       MT1, MT2, MT3, c0, c1);
    tobf16_kernel<<<ncv, 256, 0, stream>>>(x, xh, nN * DD / 8);

    // two bf16 aggregations (group-per-node)
    aggregate_bf16g<<<nagg, 256, 0, stream>>>(xh, csr, rs, agg1h, nN);
    aggregate_bf16g<<<nagg, 256, 0, stream>>>(agg1h, csr, rs, agg2h, nN);

    // single fused dense pass (512 thr, 4 f-quarters, k-unroll-4)
    tri_dense6<<<nden, 512, 0, stream>>>(agg2h, agg1h, xh, MT1, MT2, MT3,
                                         c0, c1, rs, out, nN);
}

// Round 19
// 140.220 us; speedup vs baseline: 3.0349x; 1.1361x over previous
//
#include <hip/hip_runtime.h>

#define DD 64
#define BSHIFT 7                 // 128 nodes per bucket
#define NBUCK_MAX 800
#define SEGCAP 4096

typedef unsigned short ushort_t;
typedef __attribute__((ext_vector_type(8))) short bf16x8;
typedef __attribute__((ext_vector_type(4))) short bf16x4;
typedef __attribute__((ext_vector_type(4))) float f32x4;

static __device__ __forceinline__ unsigned short f2bf(float f)
{
    unsigned u = __float_as_uint(f);
    unsigned r = (u + 0x7FFFu + ((u >> 16) & 1u)) >> 16;   // round-nearest-even
    return (unsigned short)r;
}
static __device__ __forceinline__ float bf_lo(unsigned w) { return __uint_as_float(w << 16); }
static __device__ __forceinline__ float bf_hi(unsigned w) { return __uint_as_float(w & 0xFFFF0000u); }

// ================= bucketed CSR build (no global atomics) =================

__global__ __launch_bounds__(256)
void bucket_count(const int* __restrict__ dst, int* __restrict__ partialCnt,
                  int nE, int chunk, int nbuck)
{
    __shared__ int bins[NBUCK_MAX];
    int blk = blockIdx.x, t = threadIdx.x;
    for (int i = t; i < nbuck; i += 256) bins[i] = 0;
    __syncthreads();
    int e0 = blk * chunk;
    int e1 = e0 + chunk; if (e1 > nE) e1 = nE;
    for (int e = e0 + t; e < e1; e += 256)
        atomicAdd(&bins[dst[e] >> BSHIFT], 1);
    __syncthreads();
    for (int i = t; i < nbuck; i += 256)
        partialCnt[(size_t)i * 256 + blk] = bins[i];
}

__global__ __launch_bounds__(256)
void bucket_scanblocks(int* __restrict__ partialCnt, int* __restrict__ bucketTot)
{
    __shared__ int s[256];
    int b = blockIdx.x, t = threadIdx.x;
    int v = partialCnt[(size_t)b * 256 + t];
    s[t] = v;
    __syncthreads();
    for (int off = 1; off < 256; off <<= 1) {
        int u = (t >= off) ? s[t - off] : 0;
        __syncthreads();
        s[t] += u;
        __syncthreads();
    }
    partialCnt[(size_t)b * 256 + t] = s[t] - v;   // exclusive
    if (t == 255) bucketTot[b] = s[255];
}

__global__ __launch_bounds__(1024)
void bucket_scanbase(const int* __restrict__ bucketTot, int* __restrict__ bucketBase,
                     int* __restrict__ rs, int nbuck, int nN)
{
    __shared__ int s[1024];
    int t = threadIdx.x;
    int v = (t < nbuck) ? bucketTot[t] : 0;
    s[t] = v;
    __syncthreads();
    for (int off = 1; off < 1024; off <<= 1) {
        int u = (t >= off) ? s[t - off] : 0;
        __syncthreads();
        s[t] += u;
        __syncthreads();
    }
    if (t < nbuck) bucketBase[t] = s[t] - v;
    if (t == nbuck - 1) {
        bucketBase[nbuck] = s[t];
        rs[nN] = s[t];                // == nE
    }
}

__global__ __launch_bounds__(256)
void bucket_scatter(const int* __restrict__ src, const int* __restrict__ dst,
                    const int* __restrict__ partialCnt,
                    const int* __restrict__ bucketBase,
                    int* __restrict__ buckEdges, int nE, int chunk, int nbuck)
{
    __shared__ int bins[NBUCK_MAX];
    __shared__ int wOff[NBUCK_MAX];
    int blk = blockIdx.x, t = threadIdx.x;
    for (int i = t; i < nbuck; i += 256) {
        bins[i] = 0;
        wOff[i] = bucketBase[i] + partialCnt[(size_t)i * 256 + blk];
    }
    __syncthreads();
    int e0 = blk * chunk;
    int e1 = e0 + chunk; if (e1 > nE) e1 = nE;
    for (int e = e0 + t; e < e1; e += 256) {
        int d = dst[e];
        int sv = src[e];
        int bb = d >> BSHIFT;
        int r = atomicAdd(&bins[bb], 1);
        buckEdges[wOff[bb] + r] = sv | ((d & 127) << 17);
    }
}

// C: per-bucket finalize: rs + csr + indf (deg>0 indicator), all-LDS
__global__ __launch_bounds__(256)
void bucket_finalize(const int* __restrict__ buckEdges,
                     const int* __restrict__ bucketBase,
                     int* __restrict__ rs, int* __restrict__ csr,
                     float* __restrict__ indf, int nN)
{
    __shared__ int eLds[SEGCAP];
    __shared__ int segLds[SEGCAP];
    __shared__ int deg[128];
    __shared__ int basec[128];
    __shared__ int cur[128];
    int b = blockIdx.x, t = threadIdx.x;
    int e0 = bucketBase[b], e1 = bucketBase[b + 1];
    int nb = e1 - e0;
    bool staged = (nb <= SEGCAP);
    if (t < 128) deg[t] = 0;
    __syncthreads();
    for (int i = t; i < nb; i += 256) {
        int p = buckEdges[e0 + i];
        if (staged) eLds[i] = p;
        atomicAdd(&deg[(p >> 17) & 127], 1);
    }
    __syncthreads();
    if (t < 128) basec[t] = deg[t];
    __syncthreads();
    for (int off = 1; off < 128; off <<= 1) {
        int u = 0;
        if (t < 128 && t >= off) u = basec[t - off];
        __syncthreads();
        if (t < 128) basec[t] += u;
        __syncthreads();
    }
    int nodeBase = b << BSHIFT;
    if (t < 128) {
        int node = nodeBase + t;
        int ex = basec[t] - deg[t];
        if (node < nN) {
            rs[node] = e0 + ex;
            indf[node] = deg[t] > 0 ? 1.0f : 0.0f;
        }
        cur[t] = ex;
    }
    __syncthreads();
    for (int i = t; i < nb; i += 256) {
        int p = staged ? eLds[i] : buckEdges[e0 + i];
        int dl = (p >> 17) & 127;
        int slot = atomicAdd(&cur[dl], 1);
        int sv = p & 0x1FFFF;
        if (staged) segLds[slot] = sv;
        else        csr[e0 + slot] = sv;
    }
    __syncthreads();
    if (staged)
        for (int i = t; i < nb; i += 256)
            csr[e0 + i] = segLds[i];
}

// ---------- fp32 -> bf16 conversion (8 elems/thread) ----------
__global__ __launch_bounds__(256)
void tobf16_kernel(const float* __restrict__ in, ushort_t* __restrict__ outh,
                   int nTot8)
{
    int i = blockIdx.x * 256 + threadIdx.x;
    if (i >= nTot8) return;
    float4 v0 = *(const float4*)(in + (size_t)i * 8);
    float4 v1 = *(const float4*)(in + (size_t)i * 8 + 4);
    uint4 o;
    o.x = (unsigned)f2bf(v0.x) | ((unsigned)f2bf(v0.y) << 16);
    o.y = (unsigned)f2bf(v0.z) | ((unsigned)f2bf(v0.w) << 16);
    o.z = (unsigned)f2bf(v1.x) | ((unsigned)f2bf(v1.y) << 16);
    o.w = (unsigned)f2bf(v1.z) | ((unsigned)f2bf(v1.w) << 16);
    *(uint4*)(outh + (size_t)i * 8) = o;
}

// ---------- weight precompute: collapse the two layers ----------
__global__ void prep_kernel(const float* __restrict__ W1l,
                            const float* __restrict__ W1r,
                            const float* __restrict__ W2l,
                            const float* __restrict__ W2r,
                            const float* __restrict__ b1,
                            const float* __restrict__ b2,
                            float* __restrict__ MT1, float* __restrict__ MT2,
                            float* __restrict__ MT3, float* __restrict__ c0,
                            float* __restrict__ c1)
{
    int f = blockIdx.x;      // 64 blocks
    int k = threadIdx.x;     // 64 threads
    float m1 = 0.f, m2 = 0.f, m3 = 0.f;
    for (int j = 0; j < DD; ++j) {
        float a2l = W2l[f * DD + j];
        float a2r = W2r[f * DD + j];
        float w1l = W1l[j * DD + k];
        float w1r = W1r[j * DD + k];
        m1 = fmaf(a2l, w1l, m1);
        m2 = fmaf(a2l, w1r, m2);
        m2 = fmaf(a2r, w1l, m2);
        m3 = fmaf(a2r, w1r, m3);
    }
    MT1[k * DD + f] = m1;
    MT2[k * DD + f] = m2;
    MT3[k * DD + f] = m3;
    float t1 = W2l[f * DD + k] * b1[k];
    float t0 = W2r[f * DD + k] * b1[k];
    for (int off = 1; off < 64; off <<= 1) {
        t1 += __shfl_xor(t1, off);
        t0 += __shfl_xor(t0, off);
    }
    if (k == 0) {
        c1[f] = t1;
        c0[f] = t0 + b2[f];
    }
}

// ---------- pack weights into MFMA B-fragment order (bf16) ----------
// For v_mfma_f32_16x16x32_bf16, operand elem e of lane l maps to
// k = (l>>4)*4 + (e&3) + 16*(e>>2)  (double-pumped K; consistent with the
// m156/m162 tr_b16 read pattern), col = l&15. Wp index:
// ((m*2+kt)*4+ft)*512 + lane*8 + e, value = MTm[(kt*32+k)*64 + ft*16+(l&15)].
__global__ __launch_bounds__(256)
void pack_weights(const float* __restrict__ MT1, const float* __restrict__ MT2,
                  const float* __restrict__ MT3, ushort_t* __restrict__ Wp)
{
    int idx = blockIdx.x * 256 + threadIdx.x;     // 0..12287
    if (idx >= 12288) return;
    int e    = idx & 7;
    int lane = (idx >> 3) & 63;
    int ft   = (idx >> 9) & 3;
    int kt   = (idx >> 11) & 1;
    int m    = idx >> 12;
    int kin  = ((lane >> 4) * 4) + (e & 3) + 16 * (e >> 2);
    int gk   = kt * 32 + kin;
    int f    = ft * 16 + (lane & 15);
    const float* MT = (m == 0) ? MT1 : (m == 1) ? MT2 : MT3;
    Wp[idx] = f2bf(MT[gk * DD + f]);
}

// ---------- aggregation, group-per-node: mean over neighbors ----------
__global__ __launch_bounds__(256, 4)
void aggregate_bf16g(const ushort_t* __restrict__ xh,
                     const int* __restrict__ csr,
                     const int* __restrict__ rs,
                     ushort_t* __restrict__ aggrh, int nN)
{
    int lane = threadIdx.x & 63;
    int w = threadIdx.x >> 6;
    int g  = lane >> 3;        // group 0..7: node owner
    int gl = lane & 7;         // lane within group
    int node = (blockIdx.x * 4 + w) * 8 + g;
    int valid = node < nN;
    int nd = valid ? node : nN - 1;
    int beg = rs[nd], end = rs[nd + 1];
    int deg = end - beg;

    float4 aL0 = {0,0,0,0}, aH0 = {0,0,0,0};
    float4 aL1 = {0,0,0,0}, aH1 = {0,0,0,0};
    float4 aL2 = {0,0,0,0}, aH2 = {0,0,0,0};
    float4 aL3 = {0,0,0,0}, aH3 = {0,0,0,0};

#define ROWA(S, L, H)                                                         \
    {                                                                         \
        uint4 v = *(const uint4*)(xh + (size_t)(S) * DD + gl * 8);            \
        L.x += bf_lo(v.x); L.y += bf_hi(v.x);                                 \
        L.z += bf_lo(v.y); L.w += bf_hi(v.y);                                 \
        H.x += bf_lo(v.z); H.y += bf_hi(v.z);                                 \
        H.z += bf_lo(v.w); H.w += bf_hi(v.w);                                 \
    }
#define ROWM(S, MM, L, H)                                                     \
    {                                                                         \
        uint4 v = *(const uint4*)(xh + (size_t)(S) * DD + gl * 8);            \
        L.x = fmaf(MM, bf_lo(v.x), L.x); L.y = fmaf(MM, bf_hi(v.x), L.y);     \
        L.z = fmaf(MM, bf_lo(v.y), L.z); L.w = fmaf(MM, bf_hi(v.y), L.w);     \
        H.x = fmaf(MM, bf_lo(v.z), H.x); H.y = fmaf(MM, bf_hi(v.z), H.y);     \
        H.z = fmaf(MM, bf_lo(v.w), H.z); H.w = fmaf(MM, bf_hi(v.w), H.w);     \
    }

    for (int ch = 0; ch < deg; ch += 8) {
        int ii = ch + gl;
        int myIdx = csr[(ii < deg) ? (beg + ii) : beg];
        int lb = g << 3;
        if (ch + 8 <= deg) {           // full chunk: no masks
            int s0 = __shfl(myIdx, lb + 0);
            int s1 = __shfl(myIdx, lb + 1);
            int s2 = __shfl(myIdx, lb + 2);
            int s3 = __shfl(myIdx, lb + 3);
            ROWA(s0, aL0, aH0) ROWA(s1, aL1, aH1)
            ROWA(s2, aL2, aH2) ROWA(s3, aL3, aH3)
            int s4 = __shfl(myIdx, lb + 4);
            int s5 = __shfl(myIdx, lb + 5);
            int s6 = __shfl(myIdx, lb + 6);
            int s7 = __shfl(myIdx, lb + 7);
            ROWA(s4, aL0, aH0) ROWA(s5, aL1, aH1)
            ROWA(s6, aL2, aH2) ROWA(s7, aL3, aH3)
        } else {                       // tail chunk: masked
            int rem = deg - ch;
            int s0 = __shfl(myIdx, lb + 0);
            int s1 = __shfl(myIdx, lb + 1);
            int s2 = __shfl(myIdx, lb + 2);
            int s3 = __shfl(myIdx, lb + 3);
            float m0 = (0 < rem) ? 1.f : 0.f;
            float m1 = (1 < rem) ? 1.f : 0.f;
            float m2 = (2 < rem) ? 1.f : 0.f;
            float m3 = (3 < rem) ? 1.f : 0.f;
            ROWM(s0, m0, aL0, aH0) ROWM(s1, m1, aL1, aH1)
            ROWM(s2, m2, aL2, aH2) ROWM(s3, m3, aL3, aH3)
            int s4 = __shfl(myIdx, lb + 4);
            int s5 = __shfl(myIdx, lb + 5);
            int s6 = __shfl(myIdx, lb + 6);
            int s7 = __shfl(myIdx, lb + 7);
            float m4 = (4 < rem) ? 1.f : 0.f;
            float m5 = (5 < rem) ? 1.f : 0.f;
            float m6 = (6 < rem) ? 1.f : 0.f;
            float m7 = (7 < rem) ? 1.f : 0.f;
            ROWM(s4, m4, aL0, aH0) ROWM(s5, m5, aL1, aH1)
            ROWM(s6, m6, aL2, aH2) ROWM(s7, m7, aL3, aH3)
        }
    }
#undef ROWA
#undef ROWM

    float4 L, H;
    L.x = (aL0.x + aL1.x) + (aL2.x + aL3.x);
    L.y = (aL0.y + aL1.y) + (aL2.y + aL3.y);
    L.z = (aL0.z + aL1.z) + (aL2.z + aL3.z);
    L.w = (aL0.w + aL1.w) + (aL2.w + aL3.w);
    H.x = (aH0.x + aH1.x) + (aH2.x + aH3.x);
    H.y = (aH0.y + aH1.y) + (aH2.y + aH3.y);
    H.z = (aH0.z + aH1.z) + (aH2.z + aH3.z);
    H.w = (aH0.w + aH1.w) + (aH2.w + aH3.w);
    if (valid) {
        float inv = 1.0f / (float)(deg > 0 ? deg : 1);
        uint4 o;
        o.x = (unsigned)f2bf(L.x * inv) | ((unsigned)f2bf(L.y * inv) << 16);
        o.y = (unsigned)f2bf(L.z * inv) | ((unsigned)f2bf(L.w * inv) << 16);
        o.z = (unsigned)f2bf(H.x * inv) | ((unsigned)f2bf(H.y * inv) << 16);
        o.w = (unsigned)f2bf(H.z * inv) | ((unsigned)f2bf(H.w * inv) << 16);
        *(uint4*)(aggrh + (size_t)node * DD + gl * 8) = o;
    }
}

// ---------- MFMA tri-dense: out = agg2@M1.T + agg1@M2.T + x@M3.T + bias ----
// One wave = 16 nodes x 64 f. No LDS, no barriers. A-frag from node rows
// (lane row = l&15; two 8B loads per K-half); B-frag pre-packed (coalesced
// 16B/lane, L1-hot). 24 mfma_f32_16x16x32_bf16 per wave. D layout (m89):
// row=(l>>4)*4+reg, col=l&15.
__global__ __launch_bounds__(256)
void tri_dense_mfma(const ushort_t* __restrict__ agg2h,
                    const ushort_t* __restrict__ agg1h,
                    const ushort_t* __restrict__ xh,
                    const ushort_t* __restrict__ Wp,
                    const float* __restrict__ c0,
                    const float* __restrict__ c1,
                    const float* __restrict__ indf,
                    float* __restrict__ out, int nN)
{
    int lane = threadIdx.x & 63;
    int w = threadIdx.x >> 6;
    int base = (blockIdx.x * 4 + w) * 16;
    if (base >= nN) return;
    int mrow = lane & 15;          // A row within tile / D col (=f low bits)
    int kg   = lane >> 4;          // k-group / D row-group
    f32x4 acc0 = {0,0,0,0}, acc1 = {0,0,0,0}, acc2 = {0,0,0,0}, acc3 = {0,0,0,0};

#define DO_SRC(S, m)                                                          \
    {                                                                         \
        const ushort_t* rowp = (S) + (size_t)(base + mrow) * DD + kg * 4;     \
        _Pragma("unroll")                                                     \
        for (int kt = 0; kt < 2; ++kt) {                                      \
            bf16x4 lo = *(const bf16x4*)(rowp + kt * 32);                     \
            bf16x4 hi = *(const bf16x4*)(rowp + kt * 32 + 16);                \
            bf16x8 a;                                                         \
            a[0] = lo[0]; a[1] = lo[1]; a[2] = lo[2]; a[3] = lo[3];           \
            a[4] = hi[0]; a[5] = hi[1]; a[6] = hi[2]; a[7] = hi[3];           \
            const ushort_t* wp = Wp + (((m) * 2 + kt) * 4) * 512 + lane * 8;  \
            bf16x8 b0 = *(const bf16x8*)(wp);                                 \
            bf16x8 b1 = *(const bf16x8*)(wp + 512);                           \
            bf16x8 b2 = *(const bf16x8*)(wp + 1024);                          \
            bf16x8 b3 = *(const bf16x8*)(wp + 1536);                          \
            acc0 = __builtin_amdgcn_mfma_f32_16x16x32_bf16(a, b0, acc0, 0, 0, 0); \
            acc1 = __builtin_amdgcn_mfma_f32_16x16x32_bf16(a, b1, acc1, 0, 0, 0); \
            acc2 = __builtin_amdgcn_mfma_f32_16x16x32_bf16(a, b2, acc2, 0, 0, 0); \
            acc3 = __builtin_amdgcn_mfma_f32_16x16x32_bf16(a, b3, acc3, 0, 0, 0); \
        }                                                                     \
    }
    DO_SRC(agg2h, 0)
    DO_SRC(agg1h, 1)
    DO_SRC(xh,    2)
#undef DO_SRC

    float ind0 = indf[base + kg * 4 + 0];
    float ind1 = indf[base + kg * 4 + 1];
    float ind2 = indf[base + kg * 4 + 2];
    float ind3 = indf[base + kg * 4 + 3];
#define STORE_T(ACC, ft)                                                      \
    {                                                                         \
        int f = (ft) * 16 + mrow;                                             \
        float b0v = c0[f], b1v = c1[f];                                       \
        size_t o = (size_t)(base + kg * 4) * DD + f;                          \
        out[o         ] = ACC[0] + b0v + ind0 * b1v;                          \
        out[o + DD    ] = ACC[1] + b0v + ind1 * b1v;                          \
        out[o + 2 * DD] = ACC[2] + b0v + ind2 * b1v;                          \
        out[o + 3 * DD] = ACC[3] + b0v + ind3 * b1v;                          \
    }
    STORE_T(acc0, 0) STORE_T(acc1, 1) STORE_T(acc2, 2) STORE_T(acc3, 3)
#undef STORE_T
}

extern "C" void kernel_launch(void* const* d_in, const int* in_sizes, int n_in,
                              void* d_out, int out_size, void* d_ws, size_t ws_size,
                              hipStream_t stream)
{
    const float* x   = (const float*)d_in[0];
    const int*   ei  = (const int*)d_in[1];
    const float* W1l = (const float*)d_in[2];
    const float* b1l = (const float*)d_in[3];
    const float* W1r = (const float*)d_in[4];
    const float* W2l = (const float*)d_in[5];
    const float* b2l = (const float*)d_in[6];
    const float* W2r = (const float*)d_in[7];
    float* out = (float*)d_out;

    int nN = in_sizes[0] / DD;   // 100000
    int nE = in_sizes[1] / 2;    // 1600000
    const int* src = ei;
    const int* dst = ei + nE;

    int nbuck = (nN + 127) >> BSHIFT;          // 782
    int chunk = (nE + 255) / 256;              // 6250

    // ws layout (float-sized slots):
    // rs[nN+1] | partialCnt[nbuck*256] | bucketTot[nbuck] | bucketBase[nbuck+1] |
    // csr[nE] | buckEdges[nE] | MT1,MT2,MT3[4096 ea] | c0,c1[64 ea] |
    // xh[nN*32] | agg1h[nN*32] | agg2h[nN*32] | indf[nN] | Wp[12288 bf16]
    int* rs         = (int*)d_ws;
    int* partialCnt = rs + nN + 1;
    int* bucketTot  = partialCnt + (size_t)nbuck * 256;
    int* bucketBase = bucketTot + nbuck;
    int* csr        = bucketBase + nbuck + 1;
    int* buckEdges  = csr + nE;
    size_t ofs = (size_t)(buckEdges + nE - (int*)d_ws);
    ofs = (ofs + 3) & ~(size_t)3;
    float* MT1 = (float*)d_ws + ofs;
    float* MT2 = MT1 + DD * DD;
    float* MT3 = MT2 + DD * DD;
    float* c0 = MT3 + DD * DD;
    float* c1 = c0 + DD;
    float* xh_f    = c1 + DD;
    float* agg1h_f = xh_f + (size_t)nN * 32;
    float* agg2h_f = agg1h_f + (size_t)nN * 32;
    float* indf    = agg2h_f + (size_t)nN * 32;
    ushort_t* Wp   = (ushort_t*)(indf + nN);
    ushort_t* xh    = (ushort_t*)xh_f;
    ushort_t* agg1h = (ushort_t*)agg1h_f;
    ushort_t* agg2h = (ushort_t*)agg2h_f;

    int ncv  = (nN * 32 / 4 + 255) / 256;      // tobf16 blocks
    int nagg = (nN + 31) / 32;                 // aggregate blocks
    int nmf  = (nN / 16 + 3) / 4;              // mfma dense blocks (4 waves ea)

    // CSR build — bucketed, zero global atomics, all-coalesced streams
    bucket_count<<<256, 256, 0, stream>>>(dst, partialCnt, nE, chunk, nbuck);
    bucket_scanblocks<<<nbuck, 256, 0, stream>>>(partialCnt, bucketTot);
    bucket_scanbase<<<1, 1024, 0, stream>>>(bucketTot, bucketBase, rs, nbuck, nN);
    bucket_scatter<<<256, 256, 0, stream>>>(src, dst, partialCnt, bucketBase,
                                            buckEdges, nE, chunk, nbuck);
    bucket_finalize<<<nbuck, 256, 0, stream>>>(buckEdges, bucketBase, rs, csr,
                                               indf, nN);

    // weight collapse + pack + x -> bf16
    prep_kernel<<<64, 64, 0, stream>>>(W1l, W1r, W2l, W2r, b1l, b2l,
                                       MT1, MT2, MT3, c0, c1);
    pack_weights<<<48, 256, 0, stream>>>(MT1, MT2, MT3, Wp);
    tobf16_kernel<<<ncv, 256, 0, stream>>>(x, xh, nN * DD / 8);

    // two bf16 aggregations (group-per-node)
    aggregate_bf16g<<<nagg, 256, 0, stream>>>(xh, csr, rs, agg1h, nN);
    aggregate_bf16g<<<nagg, 256, 0, stream>>>(agg1h, csr, rs, agg2h, nN);

    // MFMA dense: 16 nodes/wave, no LDS, no barriers
    tri_dense_mfma<<<nmf, 256, 0, stream>>>(agg2h, agg1h, xh, Wp,
                                            c0, c1, indf, out, nN);
}